// Round 6
// baseline (100.811 us; speedup 1.0000x reference)
//
#include <hip/hip_runtime.h>
#include <hip/hip_bf16.h>
#include <math.h>

#define EMB 1024
#define HEAD 64
#define NB 4
#define SEQ 4096
#define MTOT (NB * SEQ)
// fold 1/sqrt(64) and log2(e) into Q so softmax runs in base-2 (v_exp_f32 native)
#define QSCALE (0.125f * 1.44269504088896f)

typedef __attribute__((ext_vector_type(8))) short bf16x8;
typedef __attribute__((ext_vector_type(4))) float f32x4;
typedef __attribute__((ext_vector_type(16))) float f32x16;

static __device__ __forceinline__ unsigned short f2b(float f) {
    union { float f; unsigned u; } v; v.f = f;
    unsigned r = v.u + 0x7FFFu + ((v.u >> 16) & 1u);
    return (unsigned short)(r >> 16);
}
static __device__ __forceinline__ float b2f(unsigned short u) {
    union { unsigned u; float f; } v; v.u = ((unsigned)u) << 16; return v.f;
}
// packed f32x2 -> bf16x2 (RTNE), one instruction
static __device__ __forceinline__ unsigned pk2(float lo, float hi) {
    unsigned r;
    asm("v_cvt_pk_bf16_f32 %0, %1, %2" : "=v"(r) : "v"(lo), "v"(hi));
    return r;
}

// ---------------------------------------------------------------------------
// Kernel 1: W transpose + bf16 cast.  Wt layout: [3][64 n][1024 k]
// ---------------------------------------------------------------------------
__global__ void wt_kernel(const float* __restrict__ Wq, const float* __restrict__ Wk,
                          const float* __restrict__ Wv, unsigned short* __restrict__ Wt) {
    const int idx = blockIdx.x * 256 + threadIdx.x;   // 3*64*1024 = 196608
    const int m = idx >> 16;
    const int r = idx & 65535;
    const int n = r >> 10, k = r & 1023;
    const float* W = (m == 0) ? Wq : (m == 1) ? Wk : Wv;
    Wt[idx] = f2b(W[k * HEAD + n]);
}

// ---------------------------------------------------------------------------
// Kernel 2: fused QKV projection (x read ONCE). grid MTOT/64 = 256 blocks,
// 512 threads = 8 waves (2x waves/CU vs R2). wave w: m-rows (w&3)*16,
// n-frags (w>>2)*6 .. +5. Outputs: Q (pre-scaled), K row-major, V transposed.
// ---------------------------------------------------------------------------
__global__ __launch_bounds__(512) void proj_kernel(
    const float* __restrict__ x, const unsigned short* __restrict__ Wt3,
    const float* __restrict__ bq, const float* __restrict__ bk,
    const float* __restrict__ bv, unsigned short* __restrict__ qg,
    unsigned short* __restrict__ kg, unsigned short* __restrict__ vt) {
    __shared__ unsigned short Ax[64][72];    // +8 pad
    __shared__ unsigned short Wl[192][72];

    const int tid = threadIdx.x;
    const int wave = tid >> 6, lane = tid & 63;
    const int li = lane & 15, lg = lane >> 4;
    const int rbase = blockIdx.x * 64;
    const int mrow = (wave & 3) * 16;
    const int ngrp = (wave >> 2) * 6;

    f32x4 acc[6];
#pragma unroll
    for (int n = 0; n < 6; ++n) acc[n] = (f32x4){0.f, 0.f, 0.f, 0.f};

    const int xr = tid >> 3, xc = (tid & 7) * 8;

    for (int k0 = 0; k0 < EMB; k0 += 64) {
        __syncthreads();
        // stage x tile [64][64] fp32 -> bf16 (1 KB per wave-instr, coalesced)
        const float* xp = x + (size_t)(rbase + xr) * EMB + k0 + xc;
        const float4 t0 = *(const float4*)(xp);
        const float4 t1 = *(const float4*)(xp + 4);
        union { bf16x8 v; unsigned u[4]; } pa;
        pa.u[0] = pk2(t0.x, t0.y); pa.u[1] = pk2(t0.z, t0.w);
        pa.u[2] = pk2(t1.x, t1.y); pa.u[3] = pk2(t1.z, t1.w);
        *(bf16x8*)&Ax[xr][xc] = pa.v;
        // stage W tile [192][64]
#pragma unroll
        for (int i = 0; i < 3; ++i) {
            const int chunk = tid + 512 * i;
            const int row = chunk >> 3, c8 = (chunk & 7) * 8;
            *(bf16x8*)&Wl[row][c8] = *(const bf16x8*)(Wt3 + (size_t)row * EMB + k0 + c8);
        }
        __syncthreads();

        const bf16x8 a0 = *(const bf16x8*)&Ax[mrow + li][lg * 8];
        const bf16x8 a1 = *(const bf16x8*)&Ax[mrow + li][32 + lg * 8];
#pragma unroll
        for (int n = 0; n < 6; ++n) {
            const bf16x8 b0 = *(const bf16x8*)&Wl[(ngrp + n) * 16 + li][lg * 8];
            const bf16x8 b1 = *(const bf16x8*)&Wl[(ngrp + n) * 16 + li][32 + lg * 8];
            acc[n] = __builtin_amdgcn_mfma_f32_16x16x32_bf16(a0, b0, acc[n], 0, 0, 0);
            acc[n] = __builtin_amdgcn_mfma_f32_16x16x32_bf16(a1, b1, acc[n], 0, 0, 0);
        }
    }
    // epilogue
#pragma unroll
    for (int n = 0; n < 6; ++n) {
        const int f = ngrp + n;
        const int mat = f >> 2;
        const int nc = (f & 3) * 16 + li;
        const float bb = (mat == 0) ? bq[nc] : (mat == 1) ? bk[nc] : bv[nc];
#pragma unroll
        for (int r = 0; r < 4; ++r) {
            const int grow = rbase + mrow + lg * 4 + r;
            const float val = acc[n][r] + bb;
            if (mat == 0) {
                qg[(size_t)grow * HEAD + nc] = f2b(val * QSCALE);
            } else if (mat == 1) {
                kg[(size_t)grow * HEAD + nc] = f2b(val);
            } else {
                const int bi = grow >> 12, si = grow & 4095;
                vt[((size_t)bi * HEAD + nc) * SEQ + si] = f2b(val);
            }
        }
    }
}

// ---------------------------------------------------------------------------
// Kernel 3: flash attention, swapped-QK^T 32x32x16 MFMA, zero LDS, zero
// barriers. Flat (b, qtile32, window-of-TPW-32kv-tiles) units, one wave each.
// S^T = mfma(K, Q): lane owns q = lane&31; 16 of 32 k's in regs (other half
// in lane^32). Softmax fully in-register (1 cross-lane shfl per reduce).
// P -> PV B-frag via pk2 + 2 shfl_xor(32) per 16-k step. Partials to ws.
// ---------------------------------------------------------------------------
template<int TPW, int NWIN, int KMAX>
__global__ __launch_bounds__(256) void attn_kernel(
    const unsigned short* __restrict__ Qg, const unsigned short* __restrict__ Kg,
    const unsigned short* __restrict__ Vtg, unsigned* __restrict__ pO,
    float* __restrict__ pML) {
    const int lane = threadIdx.x & 63;
    const int ql = lane & 31, h = lane >> 5;
    const int b = blockIdx.y;
    const int w = blockIdx.x * 4 + (threadIdx.x >> 6);
    // decode (qidx, segment): segment k holds qidx >= TPW*k, count 128-TPW*k,
    // offset Ok = 128k - (TPW/2)k(k-1)
    int seg = 0;
#pragma unroll
    for (int kk = 1; kk < KMAX; ++kk)
        if (w >= 128 * kk - (TPW / 2) * kk * (kk - 1)) seg = kk;
    const int Os = 128 * seg - (TPW / 2) * seg * (seg - 1);
    const int qidx = TPW * seg + (w - Os);
    const int qa0 = qidx * 32;
    const int t0 = TPW * seg;
    const int tend = min(t0 + TPW, qidx + 1);

    const size_t qb = (size_t)b * SEQ * HEAD;
    // Q as B-operand: lane reads its q-row (q = ql), hd chunk 16s + 8h
    const unsigned short* qrow = Qg + qb + (size_t)(qa0 + ql) * HEAD + h * 8;
    bf16x8 qf[4];
#pragma unroll
    for (int s = 0; s < 4; ++s) qf[s] = *(const bf16x8*)(qrow + s * 16);

    f32x16 oa0, oa1;
#pragma unroll
    for (int r = 0; r < 16; ++r) { oa0[r] = 0.f; oa1[r] = 0.f; }
    float m = -1e30f, lsum = 0.f;

    // K as A-operand: lane reads k-row (kv0 + ql), hd chunk 16s + 8h
    const unsigned short* kptr = Kg + qb + (size_t)(t0 * 32 + ql) * HEAD + h * 8;
    // V^T as A-operand: lane reads d-row (32*dt + ql), kv chunk kv0 + 16s + 8h
    const unsigned short* vptr0 = Vtg + ((size_t)b * HEAD + ql) * SEQ + t0 * 32 + h * 8;
    const unsigned short* vptr1 = Vtg + ((size_t)b * HEAD + 32 + ql) * SEQ + t0 * 32 + h * 8;

    for (int t = t0; t < tend; ++t) {
        const bf16x8 kf0 = *(const bf16x8*)(kptr);
        const bf16x8 kf1 = *(const bf16x8*)(kptr + 16);
        const bf16x8 kf2 = *(const bf16x8*)(kptr + 32);
        const bf16x8 kf3 = *(const bf16x8*)(kptr + 48);
        kptr += 32 * HEAD;

        f32x16 st;
#pragma unroll
        for (int r = 0; r < 16; ++r) st[r] = 0.f;
        st = __builtin_amdgcn_mfma_f32_32x32x16_bf16(kf0, qf[0], st, 0, 0, 0);
        st = __builtin_amdgcn_mfma_f32_32x32x16_bf16(kf1, qf[1], st, 0, 0, 0);
        st = __builtin_amdgcn_mfma_f32_32x32x16_bf16(kf2, qf[2], st, 0, 0, 0);
        st = __builtin_amdgcn_mfma_f32_32x32x16_bf16(kf3, qf[3], st, 0, 0, 0);

        // V loads issued now; consumed after softmax (latency hidden)
        const bf16x8 vf00 = *(const bf16x8*)(vptr0);
        const bf16x8 vf01 = *(const bf16x8*)(vptr0 + 16);
        const bf16x8 vf10 = *(const bf16x8*)(vptr1);
        const bf16x8 vf11 = *(const bf16x8*)(vptr1 + 16);
        vptr0 += 32; vptr1 += 32;

        // causal mask: only the diagonal tile (t == qidx, kv0 == qa0)
        if (t == qidx) {
#pragma unroll
            for (int r = 0; r < 16; ++r) {
                const int kvl = (r & 3) + 8 * (r >> 2) + 4 * h;
                if (kvl > ql) st[r] = -1e30f;
            }
        }
        // row max: in-register tree + one cross-half shfl
        const float c0 = fmaxf(fmaxf(st[0], st[1]), fmaxf(st[2], st[3]));
        const float c1 = fmaxf(fmaxf(st[4], st[5]), fmaxf(st[6], st[7]));
        const float c2 = fmaxf(fmaxf(st[8], st[9]), fmaxf(st[10], st[11]));
        const float c3 = fmaxf(fmaxf(st[12], st[13]), fmaxf(st[14], st[15]));
        float cm = fmaxf(fmaxf(c0, c1), fmaxf(c2, c3));
        cm = fmaxf(cm, __shfl_xor(cm, 32));
        // defer-max (THR = 8 in log2 units)
        if (!__all(cm - m <= 8.0f)) {
            const float mn = fmaxf(m, cm);
            const float sc = exp2f(m - mn);
            m = mn;
            lsum *= sc;
#pragma unroll
            for (int r = 0; r < 16; ++r) { oa0[r] *= sc; oa1[r] *= sc; }
        }
#pragma unroll
        for (int r = 0; r < 16; ++r) st[r] = exp2f(st[r] - m);
        const float s0 = (st[0] + st[1]) + (st[2] + st[3]);
        const float s1 = (st[4] + st[5]) + (st[6] + st[7]);
        const float s2 = (st[8] + st[9]) + (st[10] + st[11]);
        const float s3 = (st[12] + st[13]) + (st[14] + st[15]);
        lsum += (s0 + s1) + (s2 + s3);

        // pack P -> bf16 words; w8[t] = regs (2t, 2t+1)
        unsigned w8[8];
#pragma unroll
        for (int tt = 0; tt < 8; ++tt) w8[tt] = pk2(st[2 * tt], st[2 * tt + 1]);
        // redistribute to B-frag slots: step s, slot (h,j) needs k = 16s+8h+j.
        // j0-3 from half0 words w[4s+2h], w[4s+2h+1]; j4-7 same words of half1.
        bf16x8 bf0, bf1;
        {
            const unsigned xa0 = h ? w8[0] : w8[2];
            const unsigned va0 = __shfl_xor((int)xa0, 32);
            const unsigned xb0 = h ? w8[1] : w8[3];
            const unsigned vb0 = __shfl_xor((int)xb0, 32);
            union { bf16x8 v; unsigned u[4]; } bb;
            bb.u[0] = h ? va0 : w8[0];
            bb.u[1] = h ? vb0 : w8[1];
            bb.u[2] = h ? w8[2] : va0;
            bb.u[3] = h ? w8[3] : vb0;
            bf0 = bb.v;
            const unsigned xa1 = h ? w8[4] : w8[6];
            const unsigned va1 = __shfl_xor((int)xa1, 32);
            const unsigned xb1 = h ? w8[5] : w8[7];
            const unsigned vb1 = __shfl_xor((int)xb1, 32);
            bb.u[0] = h ? va1 : w8[4];
            bb.u[1] = h ? vb1 : w8[5];
            bb.u[2] = h ? w8[6] : va1;
            bb.u[3] = h ? w8[7] : vb1;
            bf1 = bb.v;
        }
        // PV: O^T[d][q] accumulate (A = V^T, B = P^T)
        oa0 = __builtin_amdgcn_mfma_f32_32x32x16_bf16(vf00, bf0, oa0, 0, 0, 0);
        oa0 = __builtin_amdgcn_mfma_f32_32x32x16_bf16(vf01, bf1, oa0, 0, 0, 0);
        oa1 = __builtin_amdgcn_mfma_f32_32x32x16_bf16(vf10, bf0, oa1, 0, 0, 0);
        oa1 = __builtin_amdgcn_mfma_f32_32x32x16_bf16(vf11, bf1, oa1, 0, 0, 0);
    }

    // combine l across halves (each half summed different k's)
    lsum += __shfl_xor(lsum, 32);

    // write partial: O^T bf16-pairs [32 dpair][32 q] + (m, l)
    const size_t gw = (size_t)b * NWIN + w;
    unsigned* po = pO + gw * 1024;
#pragma unroll
    for (int r = 0; r < 16; r += 2) {
        const int dp = ((r & 3) >> 1) + 4 * (r >> 2) + 2 * h;   // d = 2*dp
        po[dp * 32 + ql] = pk2(oa0[r], oa0[r + 1]);
        po[(16 + dp) * 32 + ql] = pk2(oa1[r], oa1[r + 1]);
    }
    if (h == 0) {
        pML[gw * 64 + ql * 2] = m;
        pML[gw * 64 + ql * 2 + 1] = lsum;
    }
}

// ---------------------------------------------------------------------------
// Kernel 4: merge window partials. grid (128, NB), 256 threads.
// thread: ql = t&31, d-group g = t>>5 (8 d's). Coalesced pO reads.
// ---------------------------------------------------------------------------
template<int TPW, int NWIN, int KMAX>
__global__ __launch_bounds__(256) void merge_kernel(
    const unsigned* __restrict__ pO, const float* __restrict__ pML,
    float* __restrict__ out) {
    const int qidx = blockIdx.x, b = blockIdx.y;
    const int wcount = qidx / TPW + 1;
    const int t = threadIdx.x;
    const int ql = t & 31, g = t >> 5;

    float M = -1e30f;
    for (int k = 0; k < wcount; ++k) {
        const int Os = 128 * k - (TPW / 2) * k * (k - 1);
        const size_t gw = (size_t)b * NWIN + Os + (qidx - TPW * k);
        M = fmaxf(M, pML[gw * 64 + ql * 2]);
    }
    float acc[8] = {0.f, 0.f, 0.f, 0.f, 0.f, 0.f, 0.f, 0.f};
    float L = 0.f;
    for (int k = 0; k < wcount; ++k) {
        const int Os = 128 * k - (TPW / 2) * k * (k - 1);
        const size_t gw = (size_t)b * NWIN + Os + (qidx - TPW * k);
        const float mk = pML[gw * 64 + ql * 2];
        const float lk = pML[gw * 64 + ql * 2 + 1];
        const float wgt = exp2f(mk - M);
        L += wgt * lk;
#pragma unroll
        for (int i = 0; i < 4; ++i) {
            const unsigned u = pO[gw * 1024 + (size_t)(g * 4 + i) * 32 + ql];
            acc[2 * i] += wgt * b2f((unsigned short)(u & 0xFFFFu));
            acc[2 * i + 1] += wgt * b2f((unsigned short)(u >> 16));
        }
    }
    const float inv = 1.0f / L;
    float* op = out + ((size_t)b * SEQ + qidx * 32 + ql) * HEAD + g * 8;
    f32x4 o0 = {acc[0] * inv, acc[1] * inv, acc[2] * inv, acc[3] * inv};
    f32x4 o1 = {acc[4] * inv, acc[5] * inv, acc[6] * inv, acc[7] * inv};
    *(f32x4*)(op) = o0;
    *(f32x4*)(op + 4) = o1;
}

// ---------------------------------------------------------------------------
extern "C" void kernel_launch(void* const* d_in, const int* in_sizes, int n_in,
                              void* d_out, int out_size, void* d_ws, size_t ws_size,
                              hipStream_t stream) {
    const float* x  = (const float*)d_in[0];
    const float* Wq = (const float*)d_in[1];
    const float* bq = (const float*)d_in[2];
    const float* Wk = (const float*)d_in[3];
    const float* bk = (const float*)d_in[4];
    const float* Wv = (const float*)d_in[5];
    const float* bv = (const float*)d_in[6];

    unsigned short* Wt = (unsigned short*)d_ws;          // 3*64*1024
    unsigned short* qg = Wt + 3 * HEAD * EMB;            // MTOT*64 bf16 (Q, pre-scaled)
    unsigned short* kg = qg + (size_t)MTOT * HEAD;       // MTOT*64 bf16 (K)
    unsigned short* vt = kg + (size_t)MTOT * HEAD;       // [NB][HEAD][SEQ] bf16 (V^T)
    const size_t base_shorts = (size_t)3 * HEAD * EMB + (size_t)3 * MTOT * HEAD;
    unsigned* pO = (unsigned*)(vt + (size_t)MTOT * HEAD);

    wt_kernel<<<dim3(768), dim3(256), 0, stream>>>(Wq, Wk, Wv, Wt);
    proj_kernel<<<dim3(MTOT / 64), dim3(512), 0, stream>>>(x, Wt, bq, bk, bv, qg, kg, vt);

    // TPW=8 (32-kv tiles): NWIN=1088/batch; needs ~25.6 MB ws (proven available
    // in R5); fallback TPW=16 (NWIN=576) needs ~16.5 MB.
    const size_t need8 = base_shorts * 2 + (size_t)NB * 1088 * (1024 * 4 + 64 * 4);
    if (ws_size >= need8) {
        float* pML = (float*)(pO + (size_t)NB * 1088 * 1024);
        attn_kernel<8, 1088, 16><<<dim3(1088 / 4, NB), dim3(256), 0, stream>>>(qg, kg, vt, pO, pML);
        merge_kernel<8, 1088, 16><<<dim3(128, NB), dim3(256), 0, stream>>>(pO, pML, (float*)d_out);
    } else {
        float* pML = (float*)(pO + (size_t)NB * 576 * 1024);
        attn_kernel<16, 576, 8><<<dim3(576 / 4, NB), dim3(256), 0, stream>>>(qg, kg, vt, pO, pML);
        merge_kernel<16, 576, 8><<<dim3(128, NB), dim3(256), 0, stream>>>(pO, pML, (float*)d_out);
    }
}

// Round 7
// 88.755 us; speedup vs baseline: 1.1358x; 1.1358x over previous
//
#include <hip/hip_runtime.h>
#include <hip/hip_bf16.h>
#include <math.h>

#define EMB 1024
#define HEAD 64
#define NB 4
#define SEQ 4096
#define MTOT (NB * SEQ)
// fold 1/sqrt(64) and log2(e) into Q so softmax runs in base-2 (v_exp_f32 native)
#define QSCALE (0.125f * 1.44269504088896f)
#define NWIN 1088   // per batch: sum_k (128-8k), k=0..15  (flat (qidx,win) units)

typedef __attribute__((ext_vector_type(8))) short bf16x8;
typedef __attribute__((ext_vector_type(4))) float f32x4;
typedef __attribute__((ext_vector_type(16))) float f32x16;

static __device__ __forceinline__ unsigned short f2b(float f) {
    union { float f; unsigned u; } v; v.f = f;
    unsigned r = v.u + 0x7FFFu + ((v.u >> 16) & 1u);
    return (unsigned short)(r >> 16);
}
static __device__ __forceinline__ float b2f(unsigned short u) {
    union { unsigned u; float f; } v; v.u = ((unsigned)u) << 16; return v.f;
}
// packed f32x2 -> bf16x2 (RTNE), one instruction
static __device__ __forceinline__ unsigned pk2(float lo, float hi) {
    unsigned r;
    asm("v_cvt_pk_bf16_f32 %0, %1, %2" : "=v"(r) : "v"(lo), "v"(hi));
    return r;
}
// async global->LDS, 16B per lane; LDS dest = wave-uniform base + lane*16
static __device__ __forceinline__ void gl2lds(const unsigned short* g, unsigned short* l) {
    __builtin_amdgcn_global_load_lds(
        (__attribute__((address_space(1))) const void*)g,
        (__attribute__((address_space(3))) void*)l, 16, 0, 0);
}

// ---------------------------------------------------------------------------
// Kernel 1: W transpose + bf16 cast.  Wt layout: [3][64 n][1024 k]
// ---------------------------------------------------------------------------
__global__ void wt_kernel(const float* __restrict__ Wq, const float* __restrict__ Wk,
                          const float* __restrict__ Wv, unsigned short* __restrict__ Wt) {
    const int idx = blockIdx.x * 256 + threadIdx.x;   // 3*64*1024 = 196608
    const int m = idx >> 16;
    const int r = idx & 65535;
    const int n = r >> 10, k = r & 1023;
    const float* W = (m == 0) ? Wq : (m == 1) ? Wk : Wv;
    Wt[idx] = f2b(W[k * HEAD + n]);
}

// ---------------------------------------------------------------------------
// Kernel 2: fused QKV projection (x read ONCE). grid MTOT/64, 256 threads.
// (R2-exact configuration — known good; R3/R6 variants both regressed.)
// ---------------------------------------------------------------------------
__global__ __launch_bounds__(256) void proj_kernel(
    const float* __restrict__ x, const unsigned short* __restrict__ Wt3,
    const float* __restrict__ bq, const float* __restrict__ bk,
    const float* __restrict__ bv, unsigned short* __restrict__ qg,
    unsigned short* __restrict__ kg, unsigned short* __restrict__ vt) {
    __shared__ unsigned short Ax[64][72];    // +8 pad
    __shared__ unsigned short Wl[192][72];

    const int tid = threadIdx.x;
    const int wave = tid >> 6, lane = tid & 63;
    const int li = lane & 15, lg = lane >> 4;
    const int rbase = blockIdx.x * 64;

    f32x4 acc[12];
#pragma unroll
    for (int n = 0; n < 12; ++n) acc[n] = (f32x4){0.f, 0.f, 0.f, 0.f};

    const int xr = tid >> 2, xc = (tid & 3) * 16;

    for (int k0 = 0; k0 < EMB; k0 += 64) {
        __syncthreads();
        const float* xp = x + (size_t)(rbase + xr) * EMB + k0 + xc;
        float xv[16];
#pragma unroll
        for (int i = 0; i < 16; i += 4) {
            const float4 t = *(const float4*)(xp + i);
            xv[i] = t.x; xv[i + 1] = t.y; xv[i + 2] = t.z; xv[i + 3] = t.w;
        }
        union { bf16x8 v; unsigned u[4]; } pa, pb;
#pragma unroll
        for (int i = 0; i < 4; ++i) {
            pa.u[i] = pk2(xv[2 * i], xv[2 * i + 1]);
            pb.u[i] = pk2(xv[8 + 2 * i], xv[9 + 2 * i]);
        }
        *(bf16x8*)&Ax[xr][xc] = pa.v;
        *(bf16x8*)&Ax[xr][xc + 8] = pb.v;
#pragma unroll
        for (int i = 0; i < 6; ++i) {
            const int chunk = tid + 256 * i;
            const int row = chunk >> 3, c8 = (chunk & 7) * 8;
            *(bf16x8*)&Wl[row][c8] = *(const bf16x8*)(Wt3 + (size_t)row * EMB + k0 + c8);
        }
        __syncthreads();

        const bf16x8 a0 = *(const bf16x8*)&Ax[wave * 16 + li][lg * 8];
        const bf16x8 a1 = *(const bf16x8*)&Ax[wave * 16 + li][32 + lg * 8];
#pragma unroll
        for (int n = 0; n < 12; ++n) {
            const bf16x8 b0 = *(const bf16x8*)&Wl[n * 16 + li][lg * 8];
            const bf16x8 b1 = *(const bf16x8*)&Wl[n * 16 + li][32 + lg * 8];
            acc[n] = __builtin_amdgcn_mfma_f32_16x16x32_bf16(a0, b0, acc[n], 0, 0, 0);
            acc[n] = __builtin_amdgcn_mfma_f32_16x16x32_bf16(a1, b1, acc[n], 0, 0, 0);
        }
    }
#pragma unroll
    for (int n = 0; n < 12; ++n) {
        const int mat = n >> 2;
        const int nc = (n & 3) * 16 + li;
        const float bb = (mat == 0) ? bq[nc] : (mat == 1) ? bk[nc] : bv[nc];
#pragma unroll
        for (int r = 0; r < 4; ++r) {
            const int grow = rbase + wave * 16 + lg * 4 + r;
            const float val = acc[n][r] + bb;
            if (mat == 0) {
                qg[(size_t)grow * HEAD + nc] = f2b(val * QSCALE);
            } else if (mat == 1) {
                kg[(size_t)grow * HEAD + nc] = f2b(val);
            } else {
                const int bi = grow >> 12, si = grow & 4095;
                vt[((size_t)bi * HEAD + nc) * SEQ + si] = f2b(val);
            }
        }
    }
}

// ---------------------------------------------------------------------------
// Kernel 3: flash attention. Block = 4 waves sharing LDS-staged K/V tiles
// (coalesced global_load_lds, double-buffered, XOR-swizzled reads with
// pre-swizzled sources). Wave wv owns q-tile qp*4+wv (32 rows); block covers
// k-window [8*win, 8*win+8) of 32-kv tiles. Swapped QK^T (32x32x16),
// in-register softmax (R6-verified). Partials to ws, merged by kernel 4.
// ---------------------------------------------------------------------------
__global__ __launch_bounds__(256) void attn_kernel(
    const unsigned short* __restrict__ Qg, const unsigned short* __restrict__ Kg,
    const unsigned short* __restrict__ Vtg, unsigned* __restrict__ pO,
    float* __restrict__ pML) {
    __shared__ unsigned short Kl[2][2048];   // [buf][32 k-rows][64 d] swizzled
    __shared__ unsigned short Vl[2][2048];   // [buf][64 d-rows][32 kv] swizzled

    const int tid = threadIdx.x;
    const int lane = tid & 63, wv = tid >> 6;
    const int ql = lane & 31, h = lane >> 5;
    const int qp = blockIdx.x, win = blockIdx.y, b = blockIdx.z;
    const int t0 = win * 8;
    const int qmaxi = qp * 4 + 3;
    if (t0 > qmaxi) return;                       // empty window for this panel
    const int tend_blk = (t0 + 8 < qmaxi + 1) ? t0 + 8 : qmaxi + 1;
    const int qidx = qp * 4 + wv;
    const int qa0 = qidx * 32;
    const int myend = (t0 + 8 < qidx + 1) ? t0 + 8 : qidx + 1;   // may be <= t0

    const size_t qb = (size_t)b * SEQ * HEAD;
    const unsigned short* vtb = Vtg + (size_t)b * HEAD * SEQ;

    // staging sources, pre-swizzled so linear LDS dest + swizzled read match
    const int krow = tid >> 3, kch = tid & 7;     // K: row 0..31, 16B chunk 0..7
    const unsigned short* ksrc0 = Kg + qb + (size_t)krow * HEAD + ((kch ^ (krow & 7)) << 3);
    const int vrow = tid >> 2, vch = tid & 3;     // V^T: row 0..63, chunk 0..3
    const unsigned short* vsrc0 = vtb + (size_t)vrow * SEQ + ((vch ^ ((vrow >> 1) & 3)) << 3);

    // Q fragments (B-operand): lane's q-row = qa0+ql, k-chunk 16s+8h
    const unsigned short* qrow = Qg + qb + (size_t)(qa0 + ql) * HEAD + h * 8;
    bf16x8 qf[4];
#pragma unroll
    for (int s = 0; s < 4; ++s) qf[s] = *(const bf16x8*)(qrow + s * 16);

    f32x16 oa0, oa1;
#pragma unroll
    for (int r = 0; r < 16; ++r) { oa0[r] = 0.f; oa1[r] = 0.f; }
    float m = -1e30f, lsum = 0.f;

    const int swk = (ql & 7) << 4;
    const int swv = ((ql >> 1) & 3) << 4;

    // prologue: stage tile t0 into buffer 0
    {
        const int kv0 = t0 * 32;
        gl2lds(ksrc0 + (size_t)kv0 * HEAD, &Kl[0][wv * 512]);
        gl2lds(vsrc0 + kv0, &Vl[0][wv * 512]);
    }
    __syncthreads();

    for (int t = t0; t < tend_blk; ++t) {
        const int cur = (t - t0) & 1;
        if (t + 1 < tend_blk) {
            const int kv1 = (t + 1) * 32;
            gl2lds(ksrc0 + (size_t)kv1 * HEAD, &Kl[cur ^ 1][wv * 512]);
            gl2lds(vsrc0 + kv1, &Vl[cur ^ 1][wv * 512]);
        }
        if (t < myend) {
            const char* kb = (const char*)Kl[cur];
            const bf16x8 kf0 = *(const bf16x8*)(kb + ql * 128 + ((16 * h) ^ swk));
            const bf16x8 kf1 = *(const bf16x8*)(kb + ql * 128 + ((32 + 16 * h) ^ swk));
            const bf16x8 kf2 = *(const bf16x8*)(kb + ql * 128 + ((64 + 16 * h) ^ swk));
            const bf16x8 kf3 = *(const bf16x8*)(kb + ql * 128 + ((96 + 16 * h) ^ swk));

            f32x16 st;
#pragma unroll
            for (int r = 0; r < 16; ++r) st[r] = 0.f;
            st = __builtin_amdgcn_mfma_f32_32x32x16_bf16(kf0, qf[0], st, 0, 0, 0);
            st = __builtin_amdgcn_mfma_f32_32x32x16_bf16(kf1, qf[1], st, 0, 0, 0);
            st = __builtin_amdgcn_mfma_f32_32x32x16_bf16(kf2, qf[2], st, 0, 0, 0);
            st = __builtin_amdgcn_mfma_f32_32x32x16_bf16(kf3, qf[3], st, 0, 0, 0);

            const char* vbp = (const char*)Vl[cur];
            const bf16x8 vf00 = *(const bf16x8*)(vbp + ql * 64 + ((16 * h) ^ swv));
            const bf16x8 vf01 = *(const bf16x8*)(vbp + ql * 64 + ((32 + 16 * h) ^ swv));
            const bf16x8 vf10 = *(const bf16x8*)(vbp + (32 + ql) * 64 + ((16 * h) ^ swv));
            const bf16x8 vf11 = *(const bf16x8*)(vbp + (32 + ql) * 64 + ((32 + 16 * h) ^ swv));

            // causal mask: only the diagonal tile (kv0 == qa0)
            if (t == qidx) {
#pragma unroll
                for (int r = 0; r < 16; ++r) {
                    const int kvl = (r & 3) + 8 * (r >> 2) + 4 * h;
                    if (kvl > ql) st[r] = -1e30f;
                }
            }
            // row max: in-register tree + one cross-half shfl
            const float c0 = fmaxf(fmaxf(st[0], st[1]), fmaxf(st[2], st[3]));
            const float c1 = fmaxf(fmaxf(st[4], st[5]), fmaxf(st[6], st[7]));
            const float c2 = fmaxf(fmaxf(st[8], st[9]), fmaxf(st[10], st[11]));
            const float c3 = fmaxf(fmaxf(st[12], st[13]), fmaxf(st[14], st[15]));
            float cm = fmaxf(fmaxf(c0, c1), fmaxf(c2, c3));
            cm = fmaxf(cm, __shfl_xor(cm, 32));
            // defer-max (THR = 8 in log2 units)
            if (!__all(cm - m <= 8.0f)) {
                const float mn = fmaxf(m, cm);
                const float sc = exp2f(m - mn);
                m = mn;
                lsum *= sc;
#pragma unroll
                for (int r = 0; r < 16; ++r) { oa0[r] *= sc; oa1[r] *= sc; }
            }
#pragma unroll
            for (int r = 0; r < 16; ++r) st[r] = exp2f(st[r] - m);
            const float s0 = (st[0] + st[1]) + (st[2] + st[3]);
            const float s1 = (st[4] + st[5]) + (st[6] + st[7]);
            const float s2 = (st[8] + st[9]) + (st[10] + st[11]);
            const float s3 = (st[12] + st[13]) + (st[14] + st[15]);
            lsum += (s0 + s1) + (s2 + s3);

            // pack P -> bf16 words; redistribute to PV B-frag (R6-verified)
            unsigned w8[8];
#pragma unroll
            for (int tt = 0; tt < 8; ++tt) w8[tt] = pk2(st[2 * tt], st[2 * tt + 1]);
            bf16x8 bf0, bf1;
            {
                const unsigned xa0 = h ? w8[0] : w8[2];
                const unsigned va0 = __shfl_xor((int)xa0, 32);
                const unsigned xb0 = h ? w8[1] : w8[3];
                const unsigned vb0 = __shfl_xor((int)xb0, 32);
                union { bf16x8 v; unsigned u[4]; } bb;
                bb.u[0] = h ? va0 : w8[0];
                bb.u[1] = h ? vb0 : w8[1];
                bb.u[2] = h ? w8[2] : va0;
                bb.u[3] = h ? w8[3] : vb0;
                bf0 = bb.v;
                const unsigned xa1 = h ? w8[4] : w8[6];
                const unsigned va1 = __shfl_xor((int)xa1, 32);
                const unsigned xb1 = h ? w8[5] : w8[7];
                const unsigned vb1 = __shfl_xor((int)xb1, 32);
                bb.u[0] = h ? va1 : w8[4];
                bb.u[1] = h ? vb1 : w8[5];
                bb.u[2] = h ? w8[6] : va1;
                bb.u[3] = h ? w8[7] : vb1;
                bf1 = bb.v;
            }
            oa0 = __builtin_amdgcn_mfma_f32_32x32x16_bf16(vf00, bf0, oa0, 0, 0, 0);
            oa0 = __builtin_amdgcn_mfma_f32_32x32x16_bf16(vf01, bf1, oa0, 0, 0, 0);
            oa1 = __builtin_amdgcn_mfma_f32_32x32x16_bf16(vf10, bf0, oa1, 0, 0, 0);
            oa1 = __builtin_amdgcn_mfma_f32_32x32x16_bf16(vf11, bf1, oa1, 0, 0, 0);
        }
        __syncthreads();
    }

    if (t0 <= qidx) {
        lsum += __shfl_xor(lsum, 32);
        const int Ok = 128 * win - 4 * win * (win - 1);
        const size_t gw = (size_t)b * NWIN + Ok + (qidx - 8 * win);
        unsigned* po = pO + gw * 1024;
#pragma unroll
        for (int r = 0; r < 16; r += 2) {
            const int dp = ((r & 3) >> 1) + 4 * (r >> 2) + 2 * h;   // d = 2*dp
            po[dp * 32 + ql] = pk2(oa0[r], oa0[r + 1]);
            po[(16 + dp) * 32 + ql] = pk2(oa1[r], oa1[r + 1]);
        }
        if (h == 0) {
            pML[gw * 64 + ql * 2] = m;
            pML[gw * 64 + ql * 2 + 1] = lsum;
        }
    }
}

// ---------------------------------------------------------------------------
// Kernel 4: merge window partials (R6-exact, TPW=8). grid (128, NB), 256 thr.
// ---------------------------------------------------------------------------
__global__ __launch_bounds__(256) void merge_kernel(
    const unsigned* __restrict__ pO, const float* __restrict__ pML,
    float* __restrict__ out) {
    const int qidx = blockIdx.x, b = blockIdx.y;
    const int wcount = qidx / 8 + 1;
    const int t = threadIdx.x;
    const int ql = t & 31, g = t >> 5;

    float M = -1e30f;
    for (int k = 0; k < wcount; ++k) {
        const int Os = 128 * k - 4 * k * (k - 1);
        const size_t gw = (size_t)b * NWIN + Os + (qidx - 8 * k);
        M = fmaxf(M, pML[gw * 64 + ql * 2]);
    }
    float acc[8] = {0.f, 0.f, 0.f, 0.f, 0.f, 0.f, 0.f, 0.f};
    float L = 0.f;
    for (int k = 0; k < wcount; ++k) {
        const int Os = 128 * k - 4 * k * (k - 1);
        const size_t gw = (size_t)b * NWIN + Os + (qidx - 8 * k);
        const float mk = pML[gw * 64 + ql * 2];
        const float lk = pML[gw * 64 + ql * 2 + 1];
        const float wgt = exp2f(mk - M);
        L += wgt * lk;
#pragma unroll
        for (int i = 0; i < 4; ++i) {
            const unsigned u = pO[gw * 1024 + (size_t)(g * 4 + i) * 32 + ql];
            acc[2 * i] += wgt * b2f((unsigned short)(u & 0xFFFFu));
            acc[2 * i + 1] += wgt * b2f((unsigned short)(u >> 16));
        }
    }
    const float inv = 1.0f / L;
    float* op = out + ((size_t)b * SEQ + qidx * 32 + ql) * HEAD + g * 8;
    f32x4 o0 = {acc[0] * inv, acc[1] * inv, acc[2] * inv, acc[3] * inv};
    f32x4 o1 = {acc[4] * inv, acc[5] * inv, acc[6] * inv, acc[7] * inv};
    *(f32x4*)(op) = o0;
    *(f32x4*)(op + 4) = o1;
}

// ---------------------------------------------------------------------------
extern "C" void kernel_launch(void* const* d_in, const int* in_sizes, int n_in,
                              void* d_out, int out_size, void* d_ws, size_t ws_size,
                              hipStream_t stream) {
    const float* x  = (const float*)d_in[0];
    const float* Wq = (const float*)d_in[1];
    const float* bq = (const float*)d_in[2];
    const float* Wk = (const float*)d_in[3];
    const float* bk = (const float*)d_in[4];
    const float* Wv = (const float*)d_in[5];
    const float* bv = (const float*)d_in[6];

    unsigned short* Wt = (unsigned short*)d_ws;          // 3*64*1024
    unsigned short* qg = Wt + 3 * HEAD * EMB;            // MTOT*64 bf16 (Q, pre-scaled)
    unsigned short* kg = qg + (size_t)MTOT * HEAD;       // MTOT*64 bf16 (K)
    unsigned short* vt = kg + (size_t)MTOT * HEAD;       // [NB][HEAD][SEQ] bf16 (V^T)
    unsigned* pO = (unsigned*)(vt + (size_t)MTOT * HEAD);      // 4*1088*4KB partials
    float* pML = (float*)(pO + (size_t)NB * NWIN * 1024);      // 4*1088*256B (m,l)

    wt_kernel<<<dim3(768), dim3(256), 0, stream>>>(Wq, Wk, Wv, Wt);
    proj_kernel<<<dim3(MTOT / 64), dim3(256), 0, stream>>>(x, Wt, bq, bk, bv, qg, kg, vt);
    attn_kernel<<<dim3(32, 16, NB), dim3(256), 0, stream>>>(qg, kg, vt, pO, pML);
    merge_kernel<<<dim3(128, NB), dim3(256), 0, stream>>>(pO, pML, (float*)d_out);
}

// Round 8
// 85.464 us; speedup vs baseline: 1.1796x; 1.0385x over previous
//
#include <hip/hip_runtime.h>
#include <hip/hip_bf16.h>
#include <math.h>

#define EMB 1024
#define HEAD 64
#define NB 4
#define SEQ 4096
#define MTOT (NB * SEQ)
// fold 1/sqrt(64) and log2(e) into Q so softmax runs in base-2 (v_exp_f32 native)
#define QSCALE (0.125f * 1.44269504088896f)
#define NWIN 576   // per batch: sum_k (128-16k), k=0..7  (flat (qidx,win) units, TPW=16)

typedef __attribute__((ext_vector_type(8))) short bf16x8;
typedef __attribute__((ext_vector_type(4))) float f32x4;
typedef __attribute__((ext_vector_type(16))) float f32x16;

static __device__ __forceinline__ unsigned short f2b(float f) {
    union { float f; unsigned u; } v; v.f = f;
    unsigned r = v.u + 0x7FFFu + ((v.u >> 16) & 1u);
    return (unsigned short)(r >> 16);
}
static __device__ __forceinline__ float b2f(unsigned short u) {
    union { unsigned u; float f; } v; v.u = ((unsigned)u) << 16; return v.f;
}
// packed f32x2 -> bf16x2 (RTNE), one instruction
static __device__ __forceinline__ unsigned pk2(float lo, float hi) {
    unsigned r;
    asm("v_cvt_pk_bf16_f32 %0, %1, %2" : "=v"(r) : "v"(lo), "v"(hi));
    return r;
}
// async global->LDS, 16B per lane; LDS dest = wave-uniform base + lane*16
static __device__ __forceinline__ void gl2lds(const unsigned short* g, unsigned short* l) {
    __builtin_amdgcn_global_load_lds(
        (__attribute__((address_space(1))) const void*)g,
        (__attribute__((address_space(3))) void*)l, 16, 0, 0);
}

// ---------------------------------------------------------------------------
// Kernel 1: W transpose + bf16 cast.  Wt layout: [3][64 n][1024 k]
// ---------------------------------------------------------------------------
__global__ void wt_kernel(const float* __restrict__ Wq, const float* __restrict__ Wk,
                          const float* __restrict__ Wv, unsigned short* __restrict__ Wt) {
    const int idx = blockIdx.x * 256 + threadIdx.x;   // 3*64*1024 = 196608
    const int m = idx >> 16;
    const int r = idx & 65535;
    const int n = r >> 10, k = r & 1023;
    const float* W = (m == 0) ? Wq : (m == 1) ? Wk : Wv;
    Wt[idx] = f2b(W[k * HEAD + n]);
}

// ---------------------------------------------------------------------------
// Kernel 2: fused QKV projection (x read ONCE). grid MTOT/64, 256 threads.
// (R2-exact configuration — known good; R3/R6 variants both regressed.)
// ---------------------------------------------------------------------------
__global__ __launch_bounds__(256) void proj_kernel(
    const float* __restrict__ x, const unsigned short* __restrict__ Wt3,
    const float* __restrict__ bq, const float* __restrict__ bk,
    const float* __restrict__ bv, unsigned short* __restrict__ qg,
    unsigned short* __restrict__ kg, unsigned short* __restrict__ vt) {
    __shared__ unsigned short Ax[64][72];    // +8 pad
    __shared__ unsigned short Wl[192][72];

    const int tid = threadIdx.x;
    const int wave = tid >> 6, lane = tid & 63;
    const int li = lane & 15, lg = lane >> 4;
    const int rbase = blockIdx.x * 64;

    f32x4 acc[12];
#pragma unroll
    for (int n = 0; n < 12; ++n) acc[n] = (f32x4){0.f, 0.f, 0.f, 0.f};

    const int xr = tid >> 2, xc = (tid & 3) * 16;

    for (int k0 = 0; k0 < EMB; k0 += 64) {
        __syncthreads();
        const float* xp = x + (size_t)(rbase + xr) * EMB + k0 + xc;
        float xv[16];
#pragma unroll
        for (int i = 0; i < 16; i += 4) {
            const float4 t = *(const float4*)(xp + i);
            xv[i] = t.x; xv[i + 1] = t.y; xv[i + 2] = t.z; xv[i + 3] = t.w;
        }
        union { bf16x8 v; unsigned u[4]; } pa, pb;
#pragma unroll
        for (int i = 0; i < 4; ++i) {
            pa.u[i] = pk2(xv[2 * i], xv[2 * i + 1]);
            pb.u[i] = pk2(xv[8 + 2 * i], xv[9 + 2 * i]);
        }
        *(bf16x8*)&Ax[xr][xc] = pa.v;
        *(bf16x8*)&Ax[xr][xc + 8] = pb.v;
#pragma unroll
        for (int i = 0; i < 6; ++i) {
            const int chunk = tid + 256 * i;
            const int row = chunk >> 3, c8 = (chunk & 7) * 8;
            *(bf16x8*)&Wl[row][c8] = *(const bf16x8*)(Wt3 + (size_t)row * EMB + k0 + c8);
        }
        __syncthreads();

        const bf16x8 a0 = *(const bf16x8*)&Ax[wave * 16 + li][lg * 8];
        const bf16x8 a1 = *(const bf16x8*)&Ax[wave * 16 + li][32 + lg * 8];
#pragma unroll
        for (int n = 0; n < 12; ++n) {
            const bf16x8 b0 = *(const bf16x8*)&Wl[n * 16 + li][lg * 8];
            const bf16x8 b1 = *(const bf16x8*)&Wl[n * 16 + li][32 + lg * 8];
            acc[n] = __builtin_amdgcn_mfma_f32_16x16x32_bf16(a0, b0, acc[n], 0, 0, 0);
            acc[n] = __builtin_amdgcn_mfma_f32_16x16x32_bf16(a1, b1, acc[n], 0, 0, 0);
        }
    }
#pragma unroll
    for (int n = 0; n < 12; ++n) {
        const int mat = n >> 2;
        const int nc = (n & 3) * 16 + li;
        const float bb = (mat == 0) ? bq[nc] : (mat == 1) ? bk[nc] : bv[nc];
#pragma unroll
        for (int r = 0; r < 4; ++r) {
            const int grow = rbase + wave * 16 + lg * 4 + r;
            const float val = acc[n][r] + bb;
            if (mat == 0) {
                qg[(size_t)grow * HEAD + nc] = f2b(val * QSCALE);
            } else if (mat == 1) {
                kg[(size_t)grow * HEAD + nc] = f2b(val);
            } else {
                const int bi = grow >> 12, si = grow & 4095;
                vt[((size_t)bi * HEAD + nc) * SEQ + si] = f2b(val);
            }
        }
    }
}

// ---------------------------------------------------------------------------
// Kernel 3: flash attention. Block = 4 waves sharing LDS-staged 64x64 K/V
// tiles (global_load_lds, double-buffered, pre-swizzled sources). Wave wv
// owns q-tile qp*4+wv (32 rows); block covers kv window [512*win, +512) as
// 8 tiles of 64 kv. Per tile: two 32x32 S-halves, ONE softmax pass over
// 64 kv (amortized), swapped-QK^T in-register softmax (R6/R7-verified).
// ---------------------------------------------------------------------------
__global__ __launch_bounds__(256) void attn_kernel(
    const unsigned short* __restrict__ Qg, const unsigned short* __restrict__ Kg,
    const unsigned short* __restrict__ Vtg, unsigned* __restrict__ pO,
    float* __restrict__ pML) {
    __shared__ unsigned short Kl[2][4096];   // [buf][64 k-rows][64 d], 8KB
    __shared__ unsigned short Vl[2][4096];   // [buf][64 d-rows][64 kv], 8KB

    const int tid = threadIdx.x;
    const int lane = tid & 63, wv = tid >> 6;
    const int ql = lane & 31, h = lane >> 5;
    const int qp = blockIdx.x, win = blockIdx.y, b = blockIdx.z;
    const int t0 = win * 8;                       // 64-kv tile index
    const int tend_blk0 = 2 * qp + 2;             // tiles needed by panel
    if (t0 >= tend_blk0) return;
    const int tend_blk = (t0 + 8 < tend_blk0) ? t0 + 8 : tend_blk0;
    const int qidx = qp * 4 + wv;
    const int tdiag = qidx >> 1;
    const int qa0 = qidx * 32;
    const int myend = (t0 + 8 < tdiag + 1) ? t0 + 8 : tdiag + 1;   // may be <= t0

    const size_t qb = (size_t)b * SEQ * HEAD;
    const unsigned short* vtb = Vtg + (size_t)b * HEAD * SEQ;

    // staging geometry: 512 16B-chunks per 8KB tile; wave wv covers chunks
    // [wv*128, wv*128+128) in 2 issues of 64 lanes. Pre-swizzled source.
    int krow[2], koff[2];
#pragma unroll
    for (int j = 0; j < 2; ++j) {
        const int chunk = (wv * 2 + j) * 64 + lane;
        krow[j] = chunk >> 3;
        koff[j] = ((chunk & 7) ^ (krow[j] & 7)) << 3;
    }

    // Q fragments (B-operand): lane's q-row = qa0+ql, d-chunk 16s+8h
    const unsigned short* qrow = Qg + qb + (size_t)(qa0 + ql) * HEAD + h * 8;
    bf16x8 qf[4];
#pragma unroll
    for (int s = 0; s < 4; ++s) qf[s] = *(const bf16x8*)(qrow + s * 16);

    f32x16 oa0, oa1;
#pragma unroll
    for (int r = 0; r < 16; ++r) { oa0[r] = 0.f; oa1[r] = 0.f; }
    float m = -1e30f, lsum = 0.f;

    const int sw = (ql & 7) << 4;

    // prologue: stage tile t0 into buffer 0
#pragma unroll
    for (int j = 0; j < 2; ++j) {
        gl2lds(Kg + qb + (size_t)(t0 * 64 + krow[j]) * HEAD + koff[j], &Kl[0][(wv * 2 + j) * 512]);
        gl2lds(vtb + (size_t)krow[j] * SEQ + t0 * 64 + koff[j], &Vl[0][(wv * 2 + j) * 512]);
    }
    __syncthreads();

    for (int t = t0; t < tend_blk; ++t) {
        const int cur = (t - t0) & 1;
        if (t + 1 < tend_blk) {
            const int kv1 = (t + 1) * 64;
#pragma unroll
            for (int j = 0; j < 2; ++j) {
                gl2lds(Kg + qb + (size_t)(kv1 + krow[j]) * HEAD + koff[j], &Kl[cur ^ 1][(wv * 2 + j) * 512]);
                gl2lds(vtb + (size_t)krow[j] * SEQ + kv1 + koff[j], &Vl[cur ^ 1][(wv * 2 + j) * 512]);
            }
        }
        if (t < myend) {
            const char* kb = (const char*)Kl[cur];
            bf16x8 kf[2][4];
#pragma unroll
            for (int hh = 0; hh < 2; ++hh)
#pragma unroll
                for (int s = 0; s < 4; ++s)
                    kf[hh][s] = *(const bf16x8*)(kb + (hh * 32 + ql) * 128 + ((32 * s + 16 * h) ^ sw));

            f32x16 st0, st1;
#pragma unroll
            for (int r = 0; r < 16; ++r) { st0[r] = 0.f; st1[r] = 0.f; }
            __builtin_amdgcn_s_setprio(1);
#pragma unroll
            for (int s = 0; s < 4; ++s) {
                st0 = __builtin_amdgcn_mfma_f32_32x32x16_bf16(kf[0][s], qf[s], st0, 0, 0, 0);
                st1 = __builtin_amdgcn_mfma_f32_32x32x16_bf16(kf[1][s], qf[s], st1, 0, 0, 0);
            }
            __builtin_amdgcn_s_setprio(0);

            const char* vbp = (const char*)Vl[cur];
            bf16x8 vf[2][4];
#pragma unroll
            for (int dt = 0; dt < 2; ++dt)
#pragma unroll
                for (int cc = 0; cc < 4; ++cc)
                    vf[dt][cc] = *(const bf16x8*)(vbp + (dt * 32 + ql) * 128 + ((32 * cc + 16 * h) ^ sw));

            // causal mask on the diagonal tile
            if (t == tdiag) {
                if (qidx & 1) {
#pragma unroll
                    for (int r = 0; r < 16; ++r) {
                        const int kvl = (r & 3) + 8 * (r >> 2) + 4 * h;
                        if (kvl > ql) st1[r] = -1e30f;
                    }
                } else {
#pragma unroll
                    for (int r = 0; r < 16; ++r) {
                        const int kvl = (r & 3) + 8 * (r >> 2) + 4 * h;
                        if (kvl > ql) st0[r] = -1e30f;
                        st1[r] = -1e30f;
                    }
                }
            }
            // one softmax pass over 64 kv
            float cm = -1e30f;
#pragma unroll
            for (int r = 0; r < 16; ++r) cm = fmaxf(cm, fmaxf(st0[r], st1[r]));
            cm = fmaxf(cm, __shfl_xor(cm, 32));
            if (!__all(cm - m <= 8.0f)) {
                const float mn = fmaxf(m, cm);
                const float sc = exp2f(m - mn);
                m = mn;
                lsum *= sc;
#pragma unroll
                for (int r = 0; r < 16; ++r) { oa0[r] *= sc; oa1[r] *= sc; }
            }
            float ls = 0.f;
#pragma unroll
            for (int r = 0; r < 16; ++r) {
                st0[r] = exp2f(st0[r] - m);
                st1[r] = exp2f(st1[r] - m);
                ls += st0[r] + st1[r];
            }
            lsum += ls;

            // pack P -> bf16, redistribute to PV B-frags (verified pattern, x2 halves)
            bf16x8 bfv[4];
#pragma unroll
            for (int hh = 0; hh < 2; ++hh) {
                unsigned w8[8];
#pragma unroll
                for (int tt = 0; tt < 8; ++tt)
                    w8[tt] = hh ? pk2(st1[2 * tt], st1[2 * tt + 1])
                                : pk2(st0[2 * tt], st0[2 * tt + 1]);
                const unsigned xa0 = h ? w8[0] : w8[2];
                const unsigned va0 = __shfl_xor((int)xa0, 32);
                const unsigned xb0 = h ? w8[1] : w8[3];
                const unsigned vb0 = __shfl_xor((int)xb0, 32);
                union { bf16x8 v; unsigned u[4]; } bb;
                bb.u[0] = h ? va0 : w8[0];
                bb.u[1] = h ? vb0 : w8[1];
                bb.u[2] = h ? w8[2] : va0;
                bb.u[3] = h ? w8[3] : vb0;
                bfv[hh * 2] = bb.v;
                const unsigned xa1 = h ? w8[4] : w8[6];
                const unsigned va1 = __shfl_xor((int)xa1, 32);
                const unsigned xb1 = h ? w8[5] : w8[7];
                const unsigned vb1 = __shfl_xor((int)xb1, 32);
                bb.u[0] = h ? va1 : w8[4];
                bb.u[1] = h ? vb1 : w8[5];
                bb.u[2] = h ? w8[6] : va1;
                bb.u[3] = h ? w8[7] : vb1;
                bfv[hh * 2 + 1] = bb.v;
            }
            __builtin_amdgcn_s_setprio(1);
#pragma unroll
            for (int cc = 0; cc < 4; ++cc) {
                oa0 = __builtin_amdgcn_mfma_f32_32x32x16_bf16(vf[0][cc], bfv[cc], oa0, 0, 0, 0);
                oa1 = __builtin_amdgcn_mfma_f32_32x32x16_bf16(vf[1][cc], bfv[cc], oa1, 0, 0, 0);
            }
            __builtin_amdgcn_s_setprio(0);
        }
        __syncthreads();
    }

    if (t0 <= tdiag) {
        lsum += __shfl_xor(lsum, 32);
        const int Os = 128 * win - 8 * win * (win - 1);
        const size_t gw = (size_t)b * NWIN + Os + (qidx - 16 * win);
        unsigned* po = pO + gw * 1024;
#pragma unroll
        for (int r = 0; r < 16; r += 2) {
            const int dp = ((r & 3) >> 1) + 4 * (r >> 2) + 2 * h;   // d = 2*dp
            po[dp * 32 + ql] = pk2(oa0[r], oa0[r + 1]);
            po[(16 + dp) * 32 + ql] = pk2(oa1[r], oa1[r + 1]);
        }
        if (h == 0) {
            pML[gw * 64 + ql * 2] = m;
            pML[gw * 64 + ql * 2 + 1] = lsum;
        }
    }
}

// ---------------------------------------------------------------------------
// Kernel 4: merge window partials (TPW=16). grid (128, NB), 256 threads.
// ---------------------------------------------------------------------------
__global__ __launch_bounds__(256) void merge_kernel(
    const unsigned* __restrict__ pO, const float* __restrict__ pML,
    float* __restrict__ out) {
    const int qidx = blockIdx.x, b = blockIdx.y;
    const int wcount = qidx / 16 + 1;
    const int t = threadIdx.x;
    const int ql = t & 31, g = t >> 5;

    float M = -1e30f;
    for (int k = 0; k < wcount; ++k) {
        const int Os = 128 * k - 8 * k * (k - 1);
        const size_t gw = (size_t)b * NWIN + Os + (qidx - 16 * k);
        M = fmaxf(M, pML[gw * 64 + ql * 2]);
    }
    float acc[8] = {0.f, 0.f, 0.f, 0.f, 0.f, 0.f, 0.f, 0.f};
    float L = 0.f;
    for (int k = 0; k < wcount; ++k) {
        const int Os = 128 * k - 8 * k * (k - 1);
        const size_t gw = (size_t)b * NWIN + Os + (qidx - 16 * k);
        const float mk = pML[gw * 64 + ql * 2];
        const float lk = pML[gw * 64 + ql * 2 + 1];
        const float wgt = exp2f(mk - M);
        L += wgt * lk;
#pragma unroll
        for (int i = 0; i < 4; ++i) {
            const unsigned u = pO[gw * 1024 + (size_t)(g * 4 + i) * 32 + ql];
            acc[2 * i] += wgt * b2f((unsigned short)(u & 0xFFFFu));
            acc[2 * i + 1] += wgt * b2f((unsigned short)(u >> 16));
        }
    }
    const float inv = 1.0f / L;
    float* op = out + ((size_t)b * SEQ + qidx * 32 + ql) * HEAD + g * 8;
    f32x4 o0 = {acc[0] * inv, acc[1] * inv, acc[2] * inv, acc[3] * inv};
    f32x4 o1 = {acc[4] * inv, acc[5] * inv, acc[6] * inv, acc[7] * inv};
    *(f32x4*)(op) = o0;
    *(f32x4*)(op + 4) = o1;
}

// ---------------------------------------------------------------------------
extern "C" void kernel_launch(void* const* d_in, const int* in_sizes, int n_in,
                              void* d_out, int out_size, void* d_ws, size_t ws_size,
                              hipStream_t stream) {
    const float* x  = (const float*)d_in[0];
    const float* Wq = (const float*)d_in[1];
    const float* bq = (const float*)d_in[2];
    const float* Wk = (const float*)d_in[3];
    const float* bk = (const float*)d_in[4];
    const float* Wv = (const float*)d_in[5];
    const float* bv = (const float*)d_in[6];

    unsigned short* Wt = (unsigned short*)d_ws;          // 3*64*1024
    unsigned short* qg = Wt + 3 * HEAD * EMB;            // MTOT*64 bf16 (Q, pre-scaled)
    unsigned short* kg = qg + (size_t)MTOT * HEAD;       // MTOT*64 bf16 (K)
    unsigned short* vt = kg + (size_t)MTOT * HEAD;       // [NB][HEAD][SEQ] bf16 (V^T)
    unsigned* pO = (unsigned*)(vt + (size_t)MTOT * HEAD);      // 4*576*4KB partials
    float* pML = (float*)(pO + (size_t)NB * NWIN * 1024);      // 4*576*256B (m,l)

    wt_kernel<<<dim3(768), dim3(256), 0, stream>>>(Wq, Wk, Wv, Wt);
    proj_kernel<<<dim3(MTOT / 64), dim3(256), 0, stream>>>(x, Wt, bq, bk, bv, qg, kg, vt);
    attn_kernel<<<dim3(32, 8, NB), dim3(256), 0, stream>>>(qg, kg, vt, pO, pML);
    merge_kernel<<<dim3(128, NB), dim3(256), 0, stream>>>(pO, pML, (float*)d_out);
}

// Round 9
// 75.771 us; speedup vs baseline: 1.3305x; 1.1279x over previous
//
#include <hip/hip_runtime.h>
#include <hip/hip_bf16.h>
#include <math.h>

#define EMB 1024
#define HEAD 64
#define NB 4
#define SEQ 4096
#define MTOT (NB * SEQ)
// fold 1/sqrt(64) and log2(e) into Q so softmax runs in base-2 (v_exp_f32 native)
#define QSCALE (0.125f * 1.44269504088896f)

typedef __attribute__((ext_vector_type(8))) short bf16x8;
typedef __attribute__((ext_vector_type(4))) float f32x4;
typedef __attribute__((ext_vector_type(16))) float f32x16;

static __device__ __forceinline__ unsigned short f2b(float f) {
    union { float f; unsigned u; } v; v.f = f;
    unsigned r = v.u + 0x7FFFu + ((v.u >> 16) & 1u);
    return (unsigned short)(r >> 16);
}
static __device__ __forceinline__ float b2f(unsigned short u) {
    union { unsigned u; float f; } v; v.u = ((unsigned)u) << 16; return v.f;
}
// packed f32x2 -> bf16x2 (RTNE), one instruction
static __device__ __forceinline__ unsigned pk2(float lo, float hi) {
    unsigned r;
    asm("v_cvt_pk_bf16_f32 %0, %1, %2" : "=v"(r) : "v"(lo), "v"(hi));
    return r;
}
// async global->LDS, 16B per lane; LDS dest = wave-uniform base + lane*16
static __device__ __forceinline__ void gl2lds(const unsigned short* g, unsigned short* l) {
    __builtin_amdgcn_global_load_lds(
        (__attribute__((address_space(1))) const void*)g,
        (__attribute__((address_space(3))) void*)l, 16, 0, 0);
}

// ---------------------------------------------------------------------------
// Kernel 1: W transpose + bf16 cast.  Wt layout: [3][64 n][1024 k]
// ---------------------------------------------------------------------------
__global__ void wt_kernel(const float* __restrict__ Wq, const float* __restrict__ Wk,
                          const float* __restrict__ Wv, unsigned short* __restrict__ Wt) {
    const int idx = blockIdx.x * 256 + threadIdx.x;   // 3*64*1024 = 196608
    const int m = idx >> 16;
    const int r = idx & 65535;
    const int n = r >> 10, k = r & 1023;
    const float* W = (m == 0) ? Wq : (m == 1) ? Wk : Wv;
    Wt[idx] = f2b(W[k * HEAD + n]);
}

// ---------------------------------------------------------------------------
// Kernel 2: fused QKV projection (x read ONCE). M-tile 32 -> grid MTOT/32 =
// 512 blocks (2/CU, vs R2's 1/CU which left staging barriers nothing to
// overlap with). 256 threads; wave w: n-frags w*3..w*3+2, both m-frags.
// ---------------------------------------------------------------------------
__global__ __launch_bounds__(256) void proj_kernel(
    const float* __restrict__ x, const unsigned short* __restrict__ Wt3,
    const float* __restrict__ bq, const float* __restrict__ bk,
    const float* __restrict__ bv, unsigned short* __restrict__ qg,
    unsigned short* __restrict__ kg, unsigned short* __restrict__ vt) {
    __shared__ unsigned short Ax[32][72];    // +8 pad
    __shared__ unsigned short Wl[192][72];

    const int tid = threadIdx.x;
    const int wave = tid >> 6, lane = tid & 63;
    const int li = lane & 15, lg = lane >> 4;
    const int rbase = blockIdx.x * 32;

    f32x4 acc[2][3];
#pragma unroll
    for (int m = 0; m < 2; ++m)
#pragma unroll
        for (int n = 0; n < 3; ++n) acc[m][n] = (f32x4){0.f, 0.f, 0.f, 0.f};

    const int xr = tid >> 3, xc = (tid & 7) * 8;

    for (int k0 = 0; k0 < EMB; k0 += 64) {
        __syncthreads();
        // stage x tile [32][64] fp32 -> bf16
        const float* xp = x + (size_t)(rbase + xr) * EMB + k0 + xc;
        const float4 t0 = *(const float4*)(xp);
        const float4 t1 = *(const float4*)(xp + 4);
        union { bf16x8 v; unsigned u[4]; } pa;
        pa.u[0] = pk2(t0.x, t0.y); pa.u[1] = pk2(t0.z, t0.w);
        pa.u[2] = pk2(t1.x, t1.y); pa.u[3] = pk2(t1.z, t1.w);
        *(bf16x8*)&Ax[xr][xc] = pa.v;
        // stage W tile [192][64]
#pragma unroll
        for (int i = 0; i < 6; ++i) {
            const int chunk = tid + 256 * i;
            const int row = chunk >> 3, c8 = (chunk & 7) * 8;
            *(bf16x8*)&Wl[row][c8] = *(const bf16x8*)(Wt3 + (size_t)row * EMB + k0 + c8);
        }
        __syncthreads();

        const bf16x8 a0 = *(const bf16x8*)&Ax[li][lg * 8];
        const bf16x8 a1 = *(const bf16x8*)&Ax[li][32 + lg * 8];
        const bf16x8 a2 = *(const bf16x8*)&Ax[16 + li][lg * 8];
        const bf16x8 a3 = *(const bf16x8*)&Ax[16 + li][32 + lg * 8];
#pragma unroll
        for (int n = 0; n < 3; ++n) {
            const bf16x8 b0 = *(const bf16x8*)&Wl[(wave * 3 + n) * 16 + li][lg * 8];
            const bf16x8 b1 = *(const bf16x8*)&Wl[(wave * 3 + n) * 16 + li][32 + lg * 8];
            acc[0][n] = __builtin_amdgcn_mfma_f32_16x16x32_bf16(a0, b0, acc[0][n], 0, 0, 0);
            acc[0][n] = __builtin_amdgcn_mfma_f32_16x16x32_bf16(a1, b1, acc[0][n], 0, 0, 0);
            acc[1][n] = __builtin_amdgcn_mfma_f32_16x16x32_bf16(a2, b0, acc[1][n], 0, 0, 0);
            acc[1][n] = __builtin_amdgcn_mfma_f32_16x16x32_bf16(a3, b1, acc[1][n], 0, 0, 0);
        }
    }
#pragma unroll
    for (int m = 0; m < 2; ++m)
#pragma unroll
        for (int n = 0; n < 3; ++n) {
            const int f = wave * 3 + n;
            const int mat = f >> 2;
            const int nc = (f & 3) * 16 + li;
            const float bb = (mat == 0) ? bq[nc] : (mat == 1) ? bk[nc] : bv[nc];
#pragma unroll
            for (int r = 0; r < 4; ++r) {
                const int grow = rbase + m * 16 + lg * 4 + r;
                const float val = acc[m][n][r] + bb;
                if (mat == 0) {
                    qg[(size_t)grow * HEAD + nc] = f2b(val * QSCALE);
                } else if (mat == 1) {
                    kg[(size_t)grow * HEAD + nc] = f2b(val);
                } else {
                    const int bi = grow >> 12, si = grow & 4095;
                    vt[((size_t)bi * HEAD + nc) * SEQ + si] = f2b(val);
                }
            }
        }
}

// ---------------------------------------------------------------------------
// Kernel 3: flash attention (R8 inner loop verbatim; new geometry).
// Block = 4 waves, panel of 4 q-tiles (128 rows), window of W64 64-kv tiles.
// Flat grid: blocks/batch = sum_qp ceil((2qp+2)/W64); decode loop per block.
// W64=4 -> 272 blocks/batch = 1088 total = 4.25/CU (capacity 4). Every wave
// computes >= 1 tile (no idle waves, no dead blocks).
// ---------------------------------------------------------------------------
template<int W64, int NWIN>
__global__ __launch_bounds__(256) void attn_kernel(
    const unsigned short* __restrict__ Qg, const unsigned short* __restrict__ Kg,
    const unsigned short* __restrict__ Vtg, unsigned* __restrict__ pO,
    float* __restrict__ pML) {
    __shared__ unsigned short Kl[2][4096];   // [buf][64 k-rows][64 d], 8KB
    __shared__ unsigned short Vl[2][4096];   // [buf][64 d-rows][64 kv], 8KB

    const int tid = threadIdx.x;
    const int lane = tid & 63, wv = tid >> 6;
    const int ql = lane & 31, h = lane >> 5;
    const int b = blockIdx.y;
    // decode flat block index -> (panel qp, window win)
    int qp = 0, off = 0;
    for (;;) {
        const int nwq = (2 * qp + 2 + W64 - 1) / W64;
        if (off + nwq > blockIdx.x) break;
        off += nwq; ++qp;
    }
    const int win = blockIdx.x - off;
    const int t0 = win * W64;                     // 64-kv tile index
    const int tend_blk0 = 2 * qp + 2;
    const int tend_blk = (t0 + W64 < tend_blk0) ? t0 + W64 : tend_blk0;
    const int qidx = qp * 4 + wv;
    const int tdiag = qidx >> 1;
    const int qa0 = qidx * 32;
    const int myend = (t0 + W64 < tdiag + 1) ? t0 + W64 : tdiag + 1;

    const size_t qb = (size_t)b * SEQ * HEAD;
    const unsigned short* vtb = Vtg + (size_t)b * HEAD * SEQ;

    // staging geometry: 512 16B-chunks per 8KB tile; wave wv covers chunks
    // [wv*128, wv*128+128) in 2 issues of 64 lanes. Pre-swizzled source.
    int krow[2], koff[2];
#pragma unroll
    for (int j = 0; j < 2; ++j) {
        const int chunk = (wv * 2 + j) * 64 + lane;
        krow[j] = chunk >> 3;
        koff[j] = ((chunk & 7) ^ (krow[j] & 7)) << 3;
    }

    // Q fragments (B-operand): lane's q-row = qa0+ql, d-chunk 16s+8h
    const unsigned short* qrow = Qg + qb + (size_t)(qa0 + ql) * HEAD + h * 8;
    bf16x8 qf[4];
#pragma unroll
    for (int s = 0; s < 4; ++s) qf[s] = *(const bf16x8*)(qrow + s * 16);

    f32x16 oa0, oa1;
#pragma unroll
    for (int r = 0; r < 16; ++r) { oa0[r] = 0.f; oa1[r] = 0.f; }
    float m = -1e30f, lsum = 0.f;

    const int sw = (ql & 7) << 4;

    // prologue: stage tile t0 into buffer 0
#pragma unroll
    for (int j = 0; j < 2; ++j) {
        gl2lds(Kg + qb + (size_t)(t0 * 64 + krow[j]) * HEAD + koff[j], &Kl[0][(wv * 2 + j) * 512]);
        gl2lds(vtb + (size_t)krow[j] * SEQ + t0 * 64 + koff[j], &Vl[0][(wv * 2 + j) * 512]);
    }
    __syncthreads();

    for (int t = t0; t < tend_blk; ++t) {
        const int cur = (t - t0) & 1;
        if (t + 1 < tend_blk) {
            const int kv1 = (t + 1) * 64;
#pragma unroll
            for (int j = 0; j < 2; ++j) {
                gl2lds(Kg + qb + (size_t)(kv1 + krow[j]) * HEAD + koff[j], &Kl[cur ^ 1][(wv * 2 + j) * 512]);
                gl2lds(vtb + (size_t)krow[j] * SEQ + kv1 + koff[j], &Vl[cur ^ 1][(wv * 2 + j) * 512]);
            }
        }
        if (t < myend) {
            const char* kb = (const char*)Kl[cur];
            bf16x8 kf[2][4];
#pragma unroll
            for (int hh = 0; hh < 2; ++hh)
#pragma unroll
                for (int s = 0; s < 4; ++s)
                    kf[hh][s] = *(const bf16x8*)(kb + (hh * 32 + ql) * 128 + ((32 * s + 16 * h) ^ sw));

            f32x16 st0, st1;
#pragma unroll
            for (int r = 0; r < 16; ++r) { st0[r] = 0.f; st1[r] = 0.f; }
            __builtin_amdgcn_s_setprio(1);
#pragma unroll
            for (int s = 0; s < 4; ++s) {
                st0 = __builtin_amdgcn_mfma_f32_32x32x16_bf16(kf[0][s], qf[s], st0, 0, 0, 0);
                st1 = __builtin_amdgcn_mfma_f32_32x32x16_bf16(kf[1][s], qf[s], st1, 0, 0, 0);
            }
            __builtin_amdgcn_s_setprio(0);

            const char* vbp = (const char*)Vl[cur];
            bf16x8 vf[2][4];
#pragma unroll
            for (int dt = 0; dt < 2; ++dt)
#pragma unroll
                for (int cc = 0; cc < 4; ++cc)
                    vf[dt][cc] = *(const bf16x8*)(vbp + (dt * 32 + ql) * 128 + ((32 * cc + 16 * h) ^ sw));

            // causal mask on the diagonal tile
            if (t == tdiag) {
                if (qidx & 1) {
#pragma unroll
                    for (int r = 0; r < 16; ++r) {
                        const int kvl = (r & 3) + 8 * (r >> 2) + 4 * h;
                        if (kvl > ql) st1[r] = -1e30f;
                    }
                } else {
#pragma unroll
                    for (int r = 0; r < 16; ++r) {
                        const int kvl = (r & 3) + 8 * (r >> 2) + 4 * h;
                        if (kvl > ql) st0[r] = -1e30f;
                        st1[r] = -1e30f;
                    }
                }
            }
            // one softmax pass over 64 kv
            float cm = -1e30f;
#pragma unroll
            for (int r = 0; r < 16; ++r) cm = fmaxf(cm, fmaxf(st0[r], st1[r]));
            cm = fmaxf(cm, __shfl_xor(cm, 32));
            if (!__all(cm - m <= 8.0f)) {
                const float mn = fmaxf(m, cm);
                const float sc = exp2f(m - mn);
                m = mn;
                lsum *= sc;
#pragma unroll
                for (int r = 0; r < 16; ++r) { oa0[r] *= sc; oa1[r] *= sc; }
            }
            float ls = 0.f;
#pragma unroll
            for (int r = 0; r < 16; ++r) {
                st0[r] = exp2f(st0[r] - m);
                st1[r] = exp2f(st1[r] - m);
                ls += st0[r] + st1[r];
            }
            lsum += ls;

            // pack P -> bf16, redistribute to PV B-frags (verified pattern)
            bf16x8 bfv[4];
#pragma unroll
            for (int hh = 0; hh < 2; ++hh) {
                unsigned w8[8];
#pragma unroll
                for (int tt = 0; tt < 8; ++tt)
                    w8[tt] = hh ? pk2(st1[2 * tt], st1[2 * tt + 1])
                                : pk2(st0[2 * tt], st0[2 * tt + 1]);
                const unsigned xa0 = h ? w8[0] : w8[2];
                const unsigned va0 = __shfl_xor((int)xa0, 32);
                const unsigned xb0 = h ? w8[1] : w8[3];
                const unsigned vb0 = __shfl_xor((int)xb0, 32);
                union { bf16x8 v; unsigned u[4]; } bb;
                bb.u[0] = h ? va0 : w8[0];
                bb.u[1] = h ? vb0 : w8[1];
                bb.u[2] = h ? w8[2] : va0;
                bb.u[3] = h ? w8[3] : vb0;
                bfv[hh * 2] = bb.v;
                const unsigned xa1 = h ? w8[4] : w8[6];
                const unsigned va1 = __shfl_xor((int)xa1, 32);
                const unsigned xb1 = h ? w8[5] : w8[7];
                const unsigned vb1 = __shfl_xor((int)xb1, 32);
                bb.u[0] = h ? va1 : w8[4];
                bb.u[1] = h ? vb1 : w8[5];
                bb.u[2] = h ? w8[6] : va1;
                bb.u[3] = h ? w8[7] : vb1;
                bfv[hh * 2 + 1] = bb.v;
            }
            __builtin_amdgcn_s_setprio(1);
#pragma unroll
            for (int cc = 0; cc < 4; ++cc) {
                oa0 = __builtin_amdgcn_mfma_f32_32x32x16_bf16(vf[0][cc], bfv[cc], oa0, 0, 0, 0);
                oa1 = __builtin_amdgcn_mfma_f32_32x32x16_bf16(vf[1][cc], bfv[cc], oa1, 0, 0, 0);
            }
            __builtin_amdgcn_s_setprio(0);
        }
        __syncthreads();
    }

    if (t0 <= tdiag) {
        lsum += __shfl_xor(lsum, 32);
        const int Os = 128 * win - W64 * win * (win - 1);
        const size_t gw = (size_t)b * NWIN + Os + (qidx - 2 * W64 * win);
        unsigned* po = pO + gw * 1024;
#pragma unroll
        for (int r = 0; r < 16; r += 2) {
            const int dp = ((r & 3) >> 1) + 4 * (r >> 2) + 2 * h;   // d = 2*dp
            po[dp * 32 + ql] = pk2(oa0[r], oa0[r + 1]);
            po[(16 + dp) * 32 + ql] = pk2(oa1[r], oa1[r + 1]);
        }
        if (h == 0) {
            pML[gw * 64 + ql * 2] = m;
            pML[gw * 64 + ql * 2 + 1] = lsum;
        }
    }
}

// ---------------------------------------------------------------------------
// Kernel 4: merge window partials. grid (128, NB), 256 threads.
// ---------------------------------------------------------------------------
template<int W64, int NWIN>
__global__ __launch_bounds__(256) void merge_kernel(
    const unsigned* __restrict__ pO, const float* __restrict__ pML,
    float* __restrict__ out) {
    const int qidx = blockIdx.x, b = blockIdx.y;
    const int wcount = qidx / (2 * W64) + 1;
    const int t = threadIdx.x;
    const int ql = t & 31, g = t >> 5;

    float M = -1e30f;
    for (int k = 0; k < wcount; ++k) {
        const int Os = 128 * k - W64 * k * (k - 1);
        const size_t gw = (size_t)b * NWIN + Os + (qidx - 2 * W64 * k);
        M = fmaxf(M, pML[gw * 64 + ql * 2]);
    }
    float acc[8] = {0.f, 0.f, 0.f, 0.f, 0.f, 0.f, 0.f, 0.f};
    float L = 0.f;
    for (int k = 0; k < wcount; ++k) {
        const int Os = 128 * k - W64 * k * (k - 1);
        const size_t gw = (size_t)b * NWIN + Os + (qidx - 2 * W64 * k);
        const float mk = pML[gw * 64 + ql * 2];
        const float lk = pML[gw * 64 + ql * 2 + 1];
        const float wgt = exp2f(mk - M);
        L += wgt * lk;
#pragma unroll
        for (int i = 0; i < 4; ++i) {
            const unsigned u = pO[gw * 1024 + (size_t)(g * 4 + i) * 32 + ql];
            acc[2 * i] += wgt * b2f((unsigned short)(u & 0xFFFFu));
            acc[2 * i + 1] += wgt * b2f((unsigned short)(u >> 16));
        }
    }
    const float inv = 1.0f / L;
    float* op = out + ((size_t)b * SEQ + qidx * 32 + ql) * HEAD + g * 8;
    f32x4 o0 = {acc[0] * inv, acc[1] * inv, acc[2] * inv, acc[3] * inv};
    f32x4 o1 = {acc[4] * inv, acc[5] * inv, acc[6] * inv, acc[7] * inv};
    *(f32x4*)(op) = o0;
    *(f32x4*)(op + 4) = o1;
}

// ---------------------------------------------------------------------------
extern "C" void kernel_launch(void* const* d_in, const int* in_sizes, int n_in,
                              void* d_out, int out_size, void* d_ws, size_t ws_size,
                              hipStream_t stream) {
    const float* x  = (const float*)d_in[0];
    const float* Wq = (const float*)d_in[1];
    const float* bq = (const float*)d_in[2];
    const float* Wk = (const float*)d_in[3];
    const float* bk = (const float*)d_in[4];
    const float* Wv = (const float*)d_in[5];
    const float* bv = (const float*)d_in[6];

    unsigned short* Wt = (unsigned short*)d_ws;          // 3*64*1024
    unsigned short* qg = Wt + 3 * HEAD * EMB;            // MTOT*64 bf16 (Q, pre-scaled)
    unsigned short* kg = qg + (size_t)MTOT * HEAD;       // MTOT*64 bf16 (K)
    unsigned short* vt = kg + (size_t)MTOT * HEAD;       // [NB][HEAD][SEQ] bf16 (V^T)
    unsigned* pO = (unsigned*)(vt + (size_t)MTOT * HEAD);
    const size_t base_shorts = (size_t)3 * HEAD * EMB + (size_t)3 * MTOT * HEAD;

    wt_kernel<<<dim3(768), dim3(256), 0, stream>>>(Wq, Wk, Wv, Wt);
    proj_kernel<<<dim3(MTOT / 32), dim3(256), 0, stream>>>(x, Wt, bq, bk, bv, qg, kg, vt);

    // W64=4: 272 blocks/batch, NWIN=1088 partial slots/batch (~25.6 MB ws,
    // footprint proven in R5/R7). Fallback W64=8 (R8-exact, ~16.5 MB).
    const size_t need4 = base_shorts * 2 + (size_t)NB * 1088 * (1024 * 4 + 64 * 4);
    if (ws_size >= need4) {
        float* pML = (float*)(pO + (size_t)NB * 1088 * 1024);
        attn_kernel<4, 1088><<<dim3(272, NB), dim3(256), 0, stream>>>(qg, kg, vt, pO, pML);
        merge_kernel<4, 1088><<<dim3(128, NB), dim3(256), 0, stream>>>(pO, pML, (float*)d_out);
    } else {
        float* pML = (float*)(pO + (size_t)NB * 576 * 1024);
        attn_kernel<8, 576><<<dim3(144, NB), dim3(256), 0, stream>>>(qg, kg, vt, pO, pML);
        merge_kernel<8, 576><<<dim3(128, NB), dim3(256), 0, stream>>>(pO, pML, (float*)d_out);
    }
}

// Round 10
// 72.088 us; speedup vs baseline: 1.3984x; 1.0511x over previous
//
#include <hip/hip_runtime.h>
#include <hip/hip_bf16.h>
#include <math.h>

#define EMB 1024
#define HEAD 64
#define NB 4
#define SEQ 4096
#define MTOT (NB * SEQ)
// fold 1/sqrt(64) and log2(e) into Q so softmax runs in base-2 (v_exp_f32 native)
#define QSCALE (0.125f * 1.44269504088896f)

typedef __attribute__((ext_vector_type(8))) short bf16x8;
typedef __attribute__((ext_vector_type(4))) float f32x4;
typedef __attribute__((ext_vector_type(16))) float f32x16;

static __device__ __forceinline__ unsigned short f2b(float f) {
    union { float f; unsigned u; } v; v.f = f;
    unsigned r = v.u + 0x7FFFu + ((v.u >> 16) & 1u);
    return (unsigned short)(r >> 16);
}
static __device__ __forceinline__ float b2f(unsigned short u) {
    union { unsigned u; float f; } v; v.u = ((unsigned)u) << 16; return v.f;
}
// packed f32x2 -> bf16x2 (RTNE), one instruction
static __device__ __forceinline__ unsigned pk2(float lo, float hi) {
    unsigned r;
    asm("v_cvt_pk_bf16_f32 %0, %1, %2" : "=v"(r) : "v"(lo), "v"(hi));
    return r;
}

// ---------------------------------------------------------------------------
// Kernel 1: W transpose + bf16 cast.  Wt layout: [3][64 n][1024 k]
// ---------------------------------------------------------------------------
__global__ void wt_kernel(const float* __restrict__ Wq, const float* __restrict__ Wk,
                          const float* __restrict__ Wv, unsigned short* __restrict__ Wt) {
    const int idx = blockIdx.x * 256 + threadIdx.x;   // 3*64*1024 = 196608
    const int m = idx >> 16;
    const int r = idx & 65535;
    const int n = r >> 10, k = r & 1023;
    const float* W = (m == 0) ? Wq : (m == 1) ? Wk : Wv;
    Wt[idx] = f2b(W[k * HEAD + n]);
}

// ---------------------------------------------------------------------------
// Kernel 2: fused QKV projection (x read ONCE). grid MTOT/32 = 512 blocks.
// Outputs: Q row-major (pre-scaled), K in MFMA-blocked layout
// Kb[b][h][s][kv][8] (d = 16s+8h+j), V in blocked layout Vb[b][kv/8][d][8]
// -> attn fragment loads become fully coalesced dwordx4.
// ---------------------------------------------------------------------------
__global__ __launch_bounds__(256) void proj_kernel(
    const float* __restrict__ x, const unsigned short* __restrict__ Wt3,
    const float* __restrict__ bq, const float* __restrict__ bk,
    const float* __restrict__ bv, unsigned short* __restrict__ qg,
    unsigned short* __restrict__ kb, unsigned short* __restrict__ vb) {
    __shared__ unsigned short Ax[32][72];    // +8 pad
    __shared__ unsigned short Wl[192][72];

    const int tid = threadIdx.x;
    const int wave = tid >> 6, lane = tid & 63;
    const int li = lane & 15, lg = lane >> 4;
    const int rbase = blockIdx.x * 32;

    f32x4 acc[2][3];
#pragma unroll
    for (int m = 0; m < 2; ++m)
#pragma unroll
        for (int n = 0; n < 3; ++n) acc[m][n] = (f32x4){0.f, 0.f, 0.f, 0.f};

    const int xr = tid >> 3, xc = (tid & 7) * 8;

    for (int k0 = 0; k0 < EMB; k0 += 64) {
        __syncthreads();
        // stage x tile [32][64] fp32 -> bf16
        const float* xp = x + (size_t)(rbase + xr) * EMB + k0 + xc;
        const float4 t0 = *(const float4*)(xp);
        const float4 t1 = *(const float4*)(xp + 4);
        union { bf16x8 v; unsigned u[4]; } pa;
        pa.u[0] = pk2(t0.x, t0.y); pa.u[1] = pk2(t0.z, t0.w);
        pa.u[2] = pk2(t1.x, t1.y); pa.u[3] = pk2(t1.z, t1.w);
        *(bf16x8*)&Ax[xr][xc] = pa.v;
        // stage W tile [192][64]
#pragma unroll
        for (int i = 0; i < 6; ++i) {
            const int chunk = tid + 256 * i;
            const int row = chunk >> 3, c8 = (chunk & 7) * 8;
            *(bf16x8*)&Wl[row][c8] = *(const bf16x8*)(Wt3 + (size_t)row * EMB + k0 + c8);
        }
        __syncthreads();

        const bf16x8 a0 = *(const bf16x8*)&Ax[li][lg * 8];
        const bf16x8 a1 = *(const bf16x8*)&Ax[li][32 + lg * 8];
        const bf16x8 a2 = *(const bf16x8*)&Ax[16 + li][lg * 8];
        const bf16x8 a3 = *(const bf16x8*)&Ax[16 + li][32 + lg * 8];
#pragma unroll
        for (int n = 0; n < 3; ++n) {
            const bf16x8 b0 = *(const bf16x8*)&Wl[(wave * 3 + n) * 16 + li][lg * 8];
            const bf16x8 b1 = *(const bf16x8*)&Wl[(wave * 3 + n) * 16 + li][32 + lg * 8];
            acc[0][n] = __builtin_amdgcn_mfma_f32_16x16x32_bf16(a0, b0, acc[0][n], 0, 0, 0);
            acc[0][n] = __builtin_amdgcn_mfma_f32_16x16x32_bf16(a1, b1, acc[0][n], 0, 0, 0);
            acc[1][n] = __builtin_amdgcn_mfma_f32_16x16x32_bf16(a2, b0, acc[1][n], 0, 0, 0);
            acc[1][n] = __builtin_amdgcn_mfma_f32_16x16x32_bf16(a3, b1, acc[1][n], 0, 0, 0);
        }
    }
#pragma unroll
    for (int m = 0; m < 2; ++m)
#pragma unroll
        for (int n = 0; n < 3; ++n) {
            const int f = wave * 3 + n;
            const int mat = f >> 2;
            const int nc = (f & 3) * 16 + li;
            const float bb = (mat == 0) ? bq[nc] : (mat == 1) ? bk[nc] : bv[nc];
#pragma unroll
            for (int r = 0; r < 4; ++r) {
                const int grow = rbase + m * 16 + lg * 4 + r;
                const float val = acc[m][n][r] + bb;
                const int bi = grow >> 12, si = grow & 4095;
                if (mat == 0) {
                    qg[(size_t)grow * HEAD + nc] = f2b(val * QSCALE);
                } else if (mat == 1) {
                    // Kb[b][h][s][kv][8]: h=(nc>>3)&1, s=nc>>4, j=nc&7
                    kb[((size_t)(bi * 2 + ((nc >> 3) & 1)) * 4 + (nc >> 4)) * (SEQ * 8)
                       + (size_t)si * 8 + (nc & 7)] = f2b(val);
                } else {
                    // Vb[b][kv/8][d][8]: kvc=si>>3, j=si&7, d=nc
                    vb[((size_t)(bi * 512 + (si >> 3))) * 512 + (size_t)nc * 8 + (si & 7)] = f2b(val);
                }
            }
        }
}

// ---------------------------------------------------------------------------
// Kernel 3: flash attention — barrier-free, zero-LDS, fully-coalesced
// fragment loads from blocked K/V. One independent wave per flat unit
// (b, qidx, window of W64 64-kv tiles). Compute path bit-identical to the
// R8/R9-verified kernel (same fragment slot->element maps). Explicit K
// prefetch of t+1 hidden under softmax+PV; V loads hidden under softmax.
// ---------------------------------------------------------------------------
template<int W64, int NWIN, int KMAX>
__global__ __launch_bounds__(256) void attn_kernel(
    const unsigned short* __restrict__ Qg, const unsigned short* __restrict__ Kb,
    const unsigned short* __restrict__ Vb, unsigned* __restrict__ pO,
    float* __restrict__ pML) {
    const int lane = threadIdx.x & 63;
    const int ql = lane & 31, h = lane >> 5;
    const int b = blockIdx.y;
    const int w = blockIdx.x * 4 + (threadIdx.x >> 6);
    // decode flat unit -> (qidx, win): seg k exists for qidx >= 2*W64*k,
    // count 128-2*W64*k, offset Ok = 128k - W64*k*(k-1)
    int seg = 0;
#pragma unroll
    for (int kk = 1; kk < KMAX; ++kk)
        if (w >= 128 * kk - W64 * kk * (kk - 1)) seg = kk;
    const int Os = 128 * seg - W64 * seg * (seg - 1);
    const int qidx = 2 * W64 * seg + (w - Os);
    const int tdiag = qidx >> 1;
    const int qa0 = qidx * 32;
    const int t0 = W64 * seg;
    const int tend = (t0 + W64 < tdiag + 1) ? t0 + W64 : tdiag + 1;

    const size_t qb = (size_t)b * SEQ * HEAD;
    // blocked bases (offsets in shorts)
    const unsigned short* kb0 = Kb + ((size_t)(b * 2 + h)) * 4 * (SEQ * 8);
    const unsigned short* vb0 = Vb + (size_t)b * 512 * 512;

    // Q fragments (B-operand): lane's q-row = qa0+ql, d-chunk 16s+8h
    const unsigned short* qrow = Qg + qb + (size_t)(qa0 + ql) * HEAD + h * 8;
    bf16x8 qf[4];
#pragma unroll
    for (int s = 0; s < 4; ++s) qf[s] = *(const bf16x8*)(qrow + s * 16);

    f32x16 oa0, oa1;
#pragma unroll
    for (int r = 0; r < 16; ++r) { oa0[r] = 0.f; oa1[r] = 0.f; }
    float m = -1e30f, lsum = 0.f;

    // K fragment loads for tile t: kf[hh][s] = K[t*64+32hh+ql][16s+8h+j]
    bf16x8 kcur[2][4], knxt[2][4];
#pragma unroll
    for (int hh = 0; hh < 2; ++hh)
#pragma unroll
        for (int s = 0; s < 4; ++s)
            kcur[hh][s] = *(const bf16x8*)(kb0 + (size_t)s * (SEQ * 8)
                                           + ((size_t)t0 * 64 + 32 * hh + ql) * 8);

    for (int t = t0; t < tend; ++t) {
        // V fragments: vf[dt][cc] = V^T[dt*32+ql][t*64+16cc+8h+j]
        bf16x8 vf[2][4];
#pragma unroll
        for (int dt = 0; dt < 2; ++dt)
#pragma unroll
            for (int cc = 0; cc < 4; ++cc)
                vf[dt][cc] = *(const bf16x8*)(vb0 + ((size_t)t * 8 + 2 * cc + h) * 512
                                              + (dt * 32 + ql) * 8);

        f32x16 st0, st1;
#pragma unroll
        for (int r = 0; r < 16; ++r) { st0[r] = 0.f; st1[r] = 0.f; }
        __builtin_amdgcn_s_setprio(1);
#pragma unroll
        for (int s = 0; s < 4; ++s) {
            st0 = __builtin_amdgcn_mfma_f32_32x32x16_bf16(kcur[0][s], qf[s], st0, 0, 0, 0);
            st1 = __builtin_amdgcn_mfma_f32_32x32x16_bf16(kcur[1][s], qf[s], st1, 0, 0, 0);
        }
        __builtin_amdgcn_s_setprio(0);

        // prefetch K for t+1 (hidden under softmax + PV)
        if (t + 1 < tend) {
#pragma unroll
            for (int hh = 0; hh < 2; ++hh)
#pragma unroll
                for (int s = 0; s < 4; ++s)
                    knxt[hh][s] = *(const bf16x8*)(kb0 + (size_t)s * (SEQ * 8)
                                                   + ((size_t)(t + 1) * 64 + 32 * hh + ql) * 8);
        }

        // causal mask on the diagonal tile
        if (t == tdiag) {
            if (qidx & 1) {
#pragma unroll
                for (int r = 0; r < 16; ++r) {
                    const int kvl = (r & 3) + 8 * (r >> 2) + 4 * h;
                    if (kvl > ql) st1[r] = -1e30f;
                }
            } else {
#pragma unroll
                for (int r = 0; r < 16; ++r) {
                    const int kvl = (r & 3) + 8 * (r >> 2) + 4 * h;
                    if (kvl > ql) st0[r] = -1e30f;
                    st1[r] = -1e30f;
                }
            }
        }
        // one softmax pass over 64 kv
        float cm = -1e30f;
#pragma unroll
        for (int r = 0; r < 16; ++r) cm = fmaxf(cm, fmaxf(st0[r], st1[r]));
        cm = fmaxf(cm, __shfl_xor(cm, 32));
        if (!__all(cm - m <= 8.0f)) {
            const float mn = fmaxf(m, cm);
            const float sc = exp2f(m - mn);
            m = mn;
            lsum *= sc;
#pragma unroll
            for (int r = 0; r < 16; ++r) { oa0[r] *= sc; oa1[r] *= sc; }
        }
        float ls = 0.f;
#pragma unroll
        for (int r = 0; r < 16; ++r) {
            st0[r] = exp2f(st0[r] - m);
            st1[r] = exp2f(st1[r] - m);
            ls += st0[r] + st1[r];
        }
        lsum += ls;

        // pack P -> bf16, redistribute to PV B-frags (verified pattern)
        bf16x8 bfv[4];
#pragma unroll
        for (int hh = 0; hh < 2; ++hh) {
            unsigned w8[8];
#pragma unroll
            for (int tt = 0; tt < 8; ++tt)
                w8[tt] = hh ? pk2(st1[2 * tt], st1[2 * tt + 1])
                            : pk2(st0[2 * tt], st0[2 * tt + 1]);
            const unsigned xa0 = h ? w8[0] : w8[2];
            const unsigned va0 = __shfl_xor((int)xa0, 32);
            const unsigned xb0 = h ? w8[1] : w8[3];
            const unsigned vb_0 = __shfl_xor((int)xb0, 32);
            union { bf16x8 v; unsigned u[4]; } bbv;
            bbv.u[0] = h ? va0 : w8[0];
            bbv.u[1] = h ? vb_0 : w8[1];
            bbv.u[2] = h ? w8[2] : va0;
            bbv.u[3] = h ? w8[3] : vb_0;
            bfv[hh * 2] = bbv.v;
            const unsigned xa1 = h ? w8[4] : w8[6];
            const unsigned va1 = __shfl_xor((int)xa1, 32);
            const unsigned xb1 = h ? w8[5] : w8[7];
            const unsigned vb_1 = __shfl_xor((int)xb1, 32);
            bbv.u[0] = h ? va1 : w8[4];
            bbv.u[1] = h ? vb_1 : w8[5];
            bbv.u[2] = h ? w8[6] : va1;
            bbv.u[3] = h ? w8[7] : vb_1;
            bfv[hh * 2 + 1] = bbv.v;
        }
        __builtin_amdgcn_s_setprio(1);
#pragma unroll
        for (int cc = 0; cc < 4; ++cc) {
            oa0 = __builtin_amdgcn_mfma_f32_32x32x16_bf16(vf[0][cc], bfv[cc], oa0, 0, 0, 0);
            oa1 = __builtin_amdgcn_mfma_f32_32x32x16_bf16(vf[1][cc], bfv[cc], oa1, 0, 0, 0);
        }
        __builtin_amdgcn_s_setprio(0);

        // rotate prefetched K into place (static indices only)
#pragma unroll
        for (int hh = 0; hh < 2; ++hh)
#pragma unroll
            for (int s = 0; s < 4; ++s)
                kcur[hh][s] = knxt[hh][s];
    }

    lsum += __shfl_xor(lsum, 32);
    const size_t gw = (size_t)b * NWIN + w;
    unsigned* po = pO + gw * 1024;
#pragma unroll
    for (int r = 0; r < 16; r += 2) {
        const int dp = ((r & 3) >> 1) + 4 * (r >> 2) + 2 * h;   // d = 2*dp
        po[dp * 32 + ql] = pk2(oa0[r], oa0[r + 1]);
        po[(16 + dp) * 32 + ql] = pk2(oa1[r], oa1[r + 1]);
    }
    if (h == 0) {
        pML[gw * 64 + ql * 2] = m;
        pML[gw * 64 + ql * 2 + 1] = lsum;
    }
}

// ---------------------------------------------------------------------------
// Kernel 4: merge window partials (R9-exact algebra). grid (128, NB), 256 thr.
// ---------------------------------------------------------------------------
template<int W64, int NWIN>
__global__ __launch_bounds__(256) void merge_kernel(
    const unsigned* __restrict__ pO, const float* __restrict__ pML,
    float* __restrict__ out) {
    const int qidx = blockIdx.x, b = blockIdx.y;
    const int wcount = qidx / (2 * W64) + 1;
    const int t = threadIdx.x;
    const int ql = t & 31, g = t >> 5;

    float M = -1e30f;
    for (int k = 0; k < wcount; ++k) {
        const int Os = 128 * k - W64 * k * (k - 1);
        const size_t gw = (size_t)b * NWIN + Os + (qidx - 2 * W64 * k);
        M = fmaxf(M, pML[gw * 64 + ql * 2]);
    }
    float acc[8] = {0.f, 0.f, 0.f, 0.f, 0.f, 0.f, 0.f, 0.f};
    float L = 0.f;
    for (int k = 0; k < wcount; ++k) {
        const int Os = 128 * k - W64 * k * (k - 1);
        const size_t gw = (size_t)b * NWIN + Os + (qidx - 2 * W64 * k);
        const float mk = pML[gw * 64 + ql * 2];
        const float lk = pML[gw * 64 + ql * 2 + 1];
        const float wgt = exp2f(mk - M);
        L += wgt * lk;
#pragma unroll
        for (int i = 0; i < 4; ++i) {
            const unsigned u = pO[gw * 1024 + (size_t)(g * 4 + i) * 32 + ql];
            acc[2 * i] += wgt * b2f((unsigned short)(u & 0xFFFFu));
            acc[2 * i + 1] += wgt * b2f((unsigned short)(u >> 16));
        }
    }
    const float inv = 1.0f / L;
    float* op = out + ((size_t)b * SEQ + qidx * 32 + ql) * HEAD + g * 8;
    f32x4 o0 = {acc[0] * inv, acc[1] * inv, acc[2] * inv, acc[3] * inv};
    f32x4 o1 = {acc[4] * inv, acc[5] * inv, acc[6] * inv, acc[7] * inv};
    *(f32x4*)(op) = o0;
    *(f32x4*)(op + 4) = o1;
}

// ---------------------------------------------------------------------------
extern "C" void kernel_launch(void* const* d_in, const int* in_sizes, int n_in,
                              void* d_out, int out_size, void* d_ws, size_t ws_size,
                              hipStream_t stream) {
    const float* x  = (const float*)d_in[0];
    const float* Wq = (const float*)d_in[1];
    const float* bq = (const float*)d_in[2];
    const float* Wk = (const float*)d_in[3];
    const float* bk = (const float*)d_in[4];
    const float* Wv = (const float*)d_in[5];
    const float* bv = (const float*)d_in[6];

    unsigned short* Wt = (unsigned short*)d_ws;          // 3*64*1024
    unsigned short* qg = Wt + 3 * HEAD * EMB;            // MTOT*64 bf16 (Q, pre-scaled)
    unsigned short* kb = qg + (size_t)MTOT * HEAD;       // MTOT*64 bf16 (K, blocked)
    unsigned short* vb = kb + (size_t)MTOT * HEAD;       // MTOT*64 bf16 (V, blocked)
    unsigned* pO = (unsigned*)(vb + (size_t)MTOT * HEAD);
    const size_t base_shorts = (size_t)3 * HEAD * EMB + (size_t)3 * MTOT * HEAD;

    wt_kernel<<<dim3(768), dim3(256), 0, stream>>>(Wq, Wk, Wv, Wt);
    proj_kernel<<<dim3(MTOT / 32), dim3(256), 0, stream>>>(x, Wt, bq, bk, bv, qg, kb, vb);

    // W64=4: 1088 units/batch (ws footprint proven in R9). Fallback W64=8.
    const size_t need4 = base_shorts * 2 + (size_t)NB * 1088 * (1024 * 4 + 64 * 4);
    if (ws_size >= need4) {
        float* pML = (float*)(pO + (size_t)NB * 1088 * 1024);
        attn_kernel<4, 1088, 16><<<dim3(272, NB), dim3(256), 0, stream>>>(qg, kb, vb, pO, pML);
        merge_kernel<4, 1088><<<dim3(128, NB), dim3(256), 0, stream>>>(pO, pML, (float*)d_out);
    } else {
        float* pML = (float*)(pO + (size_t)NB * 576 * 1024);
        attn_kernel<8, 576, 8><<<dim3(144, NB), dim3(256), 0, stream>>>(qg, kb, vb, pO, pML);
        merge_kernel<8, 576><<<dim3(128, NB), dim3(256), 0, stream>>>(pO, pML, (float*)d_out);
    }
}